// Round 2
// baseline (241.461 us; speedup 1.0000x reference)
//
#include <hip/hip_runtime.h>

typedef __attribute__((ext_vector_type(8))) short short8;
typedef __attribute__((ext_vector_type(4))) float f32x4;
typedef unsigned short u16;

#define SCALE 0.125f

#define BB 16
#define LL 1024
#define CC 512
#define HH 8
#define DD 64
#define MROWS (BB*LL)      /* 16384 */
#define KPROJ 1024
#define NPROJ 1536

#define BM 128
#define BN 128
#define BK 32

// workspace offsets (bytes)
#define WS_XCAT   0ull
#define WS_WCAT   (WS_XCAT + (size_t)MROWS*KPROJ*2)
#define WS_WO     (WS_WCAT + (size_t)NPROJ*KPROJ*2)
#define WS_BIAS   (WS_WO   + (size_t)CC*CC*2)
#define WS_QH     (WS_BIAS + 8192)
#define WS_KH     (WS_QH + (size_t)MROWS*CC*2)
#define WS_VT     (WS_KH + (size_t)MROWS*CC*2)
#define WS_OH     (WS_VT + (size_t)MROWS*CC*2)
#define WS_END    (WS_OH + (size_t)MROWS*CC*2)

__device__ inline short f2bf(float f) {
  unsigned u = __builtin_bit_cast(unsigned, f);
  u = (u + 0x7FFFu + ((u >> 16) & 1u)) >> 16;
  return (short)u;
}

__device__ inline short8 pack8(const float* src) {
  float4 a = ((const float4*)src)[0];
  float4 b = ((const float4*)src)[1];
  short8 v;
  v[0]=f2bf(a.x); v[1]=f2bf(a.y); v[2]=f2bf(a.z); v[3]=f2bf(a.w);
  v[4]=f2bf(b.x); v[5]=f2bf(b.y); v[6]=f2bf(b.z); v[7]=f2bf(b.w);
  return v;
}

__device__ inline void gload_lds16(const u16* g, char* lds_byte) {
  __builtin_amdgcn_global_load_lds(
      (const __attribute__((address_space(1))) unsigned int*)g,
      (__attribute__((address_space(3))) unsigned int*)lds_byte,
      16, 0, 0);
}

// ---------------- pack kernels ----------------

__global__ __launch_bounds__(256) void pack_x_kernel(
    const float* __restrict__ q, const float* __restrict__ qp, u16* __restrict__ xcat) {
  int o = blockIdx.x * 256 + threadIdx.x;
  int row = o >> 7;
  int kk  = (o & 127) << 3;
  const float* src = (kk < 512) ? (q + (size_t)row * 512 + kk)
                                : (qp + (size_t)row * 512 + (kk - 512));
  short8 v = pack8(src);
  *(short8*)(xcat + (size_t)row * KPROJ + kk) = v;
}

__global__ __launch_bounds__(256) void pack_w_kernel(
    const float* __restrict__ Wqc, const float* __restrict__ Wqp,
    const float* __restrict__ Wkc, const float* __restrict__ Wkp,
    const float* __restrict__ Wv,  const float* __restrict__ Wo,
    const float* __restrict__ bqc, const float* __restrict__ bqp,
    const float* __restrict__ bkc, const float* __restrict__ bkp,
    const float* __restrict__ bv,
    u16* __restrict__ wcat, u16* __restrict__ wo_bf, float* __restrict__ bias_cat) {
  int o = blockIdx.x * 256 + threadIdx.x;
  if (o < 196608) {
    int j = o >> 7;
    int kk = (o & 127) << 3;
    const float* src = nullptr;
    if (j < 512)        src = (kk < 512) ? Wqc + (size_t)j * 512 + kk : Wqp + (size_t)j * 512 + (kk - 512);
    else if (j < 1024) { int jj = j - 512;  src = (kk < 512) ? Wkc + (size_t)jj * 512 + kk : Wkp + (size_t)jj * 512 + (kk - 512); }
    else               { int jj = j - 1024; src = (kk < 512) ? Wv  + (size_t)jj * 512 + kk : nullptr; }
    short8 v = {0,0,0,0,0,0,0,0};
    if (src) v = pack8(src);
    *(short8*)(wcat + (size_t)j * KPROJ + kk) = v;
  } else if (o < 229376) {
    int o2 = o - 196608;
    int j = o2 >> 6;
    int kk = (o2 & 63) << 3;
    short8 v = pack8(Wo + (size_t)j * 512 + kk);
    *(short8*)(wo_bf + (size_t)j * 512 + kk) = v;
  }
  if (o < 1536) {
    float v;
    if (o < 512)       v = bqc[o] + bqp[o];
    else if (o < 1024) v = bkc[o - 512] + bkp[o - 512];
    else               v = bv[o - 1024];
    bias_cat[o] = v;
  }
}

// ---------------- GEMM core ----------------
template <int KDIM>
__device__ inline void gemm_mainloop(const u16* __restrict__ A, const u16* __restrict__ Bw,
                                     int m0, int n0,
                                     u16* Alds, u16* Blds,
                                     f32x4 (&acc)[4][4]) {
  const int tid = threadIdx.x;
  const int lane = tid & 63, wave = tid >> 6;
  const int wr = wave >> 1, wc = wave & 1;
  const int lr = lane & 15, lg = lane >> 4;

  auto stage = [&](int buf, int t) {
    int k0 = t * BK;
    #pragma unroll
    for (int i = 0; i < 2; ++i) {
      int c = (i * 4 + wave) * 64 + lane;
      int row = c >> 2, koct = c & 3;
      char* ldsbaseA = (char*)Alds + (size_t)buf * (BM * BK * 2) + (size_t)(i * 4 + wave) * 1024;
      char* ldsbaseB = (char*)Blds + (size_t)buf * (BN * BK * 2) + (size_t)(i * 4 + wave) * 1024;
      gload_lds16(A  + (size_t)(m0 + row) * KDIM + k0 + koct * 8, ldsbaseA);
      gload_lds16(Bw + (size_t)(n0 + row) * KDIM + k0 + koct * 8, ldsbaseB);
    }
  };

  stage(0, 0);
  constexpr int NT = KDIM / BK;
  int cur = 0;
  for (int t = 0; t < NT; ++t) {
    __syncthreads();
    if (t + 1 < NT) stage(cur ^ 1, t + 1);
    const u16* Ab = Alds + (size_t)cur * (BM * BK);
    const u16* Bb = Blds + (size_t)cur * (BN * BK);
    short8 af[4], bfr[4];
    #pragma unroll
    for (int m = 0; m < 4; ++m)
      af[m] = *(const short8*)(Ab + (size_t)(wr * 64 + m * 16 + lr) * BK + lg * 8);
    #pragma unroll
    for (int n = 0; n < 4; ++n)
      bfr[n] = *(const short8*)(Bb + (size_t)(wc * 64 + n * 16 + lr) * BK + lg * 8);
    #pragma unroll
    for (int m = 0; m < 4; ++m)
      #pragma unroll
      for (int n = 0; n < 4; ++n)
        acc[m][n] = __builtin_amdgcn_mfma_f32_16x16x32_bf16(af[m], bfr[n], acc[m][n], 0, 0, 0);
    cur ^= 1;
  }
}

// ---------------- projection GEMM ----------------
__global__ __launch_bounds__(256) void proj_gemm_kernel(
    const u16* __restrict__ Xcat, const u16* __restrict__ Wcat,
    const float* __restrict__ bias_cat,
    u16* __restrict__ Qh, u16* __restrict__ Kh, u16* __restrict__ Vt) {
  __shared__ __align__(16) u16 Alds[2 * BM * BK];
  __shared__ __align__(16) u16 Blds[2 * BN * BK];
  int m0 = blockIdx.x * BM, n0 = blockIdx.y * BN;
  f32x4 acc[4][4];
  f32x4 z4 = {0.f, 0.f, 0.f, 0.f};
  #pragma unroll
  for (int m = 0; m < 4; ++m)
    #pragma unroll
    for (int n = 0; n < 4; ++n) acc[m][n] = z4;

  gemm_mainloop<KPROJ>(Xcat, Wcat, m0, n0, Alds, Blds, acc);

  const int lane = threadIdx.x & 63, wave = threadIdx.x >> 6;
  const int wr = wave >> 1, wc = wave & 1;
  const int lr = lane & 15, lg = lane >> 4;
  #pragma unroll
  for (int m = 0; m < 4; ++m) {
    int rowb = m0 + wr * 64 + m * 16 + lg * 4;
    #pragma unroll
    for (int n = 0; n < 4; ++n) {
      int col = n0 + wc * 64 + n * 16 + lr;
      float bias = bias_cat[col];
      int sec = col >> 9;
      int cj = col & 511;
      int h = cj >> 6, d = cj & 63;
      #pragma unroll
      for (int r = 0; r < 4; ++r) {
        int rw = rowb + r;
        int b = rw >> 10, l = rw & 1023;
        float v = acc[m][n][r] + bias;
        if (sec == 0)
          Qh[((size_t)(b * HH + h) * LL + l) * DD + d] = (u16)f2bf(v * SCALE);
        else if (sec == 1)
          Kh[((size_t)(b * HH + h) * LL + l) * DD + d] = (u16)f2bf(v);
        else
          Vt[((size_t)(b * HH + h) * DD + d) * LL + l] = (u16)f2bf(v);
      }
    }
  }
}

// ---------------- flash attention ----------------
// grid: (L/128, B*H). 4 waves, each owns 32 q rows (2 m-frags). KV tiles of 64.
// K LDS tile: [key][d] with XOR-swizzled 16B chunks; V LDS tile: [d][key] (from
// global V^T) likewise. Double-buffered, counted vmcnt, raw barriers (T3/T4).
__global__ __launch_bounds__(256, 3) void attn_kernel(
    const u16* __restrict__ Qh, const u16* __restrict__ Kh,
    const u16* __restrict__ Vt, u16* __restrict__ Oh) {
  __shared__ __align__(16) u16 Kl[2][64 * 64];
  __shared__ __align__(16) u16 Vl[2][64 * 64];
  __shared__ __align__(16) u16 Pl[4][32 * 72];

  const int tid = threadIdx.x;
  const int lane = tid & 63, wave = tid >> 6;
  const int lr = lane & 15, lg = lane >> 4;
  const int q0 = blockIdx.x * 128;
  const int bh = blockIdx.y;

  const u16* Qb = Qh + (size_t)bh * LL * DD;
  const u16* Kb = Kh + (size_t)bh * LL * DD;
  const u16* Vb = Vt + (size_t)bh * DD * LL;

  // Q fragments: aq[m][s] covers rows q0 + wave*32 + m*16 + lr, k = s*32+lg*8
  short8 aq[2][2];
  #pragma unroll
  for (int m = 0; m < 2; ++m)
    #pragma unroll
    for (int s = 0; s < 2; ++s)
      aq[m][s] = *(const short8*)(Qb + (size_t)(q0 + wave * 32 + m * 16 + lr) * DD + s * 32 + lg * 8);

  f32x4 z4 = {0.f, 0.f, 0.f, 0.f};
  f32x4 oacc[2][4];
  #pragma unroll
  for (int m = 0; m < 2; ++m)
    #pragma unroll
    for (int n = 0; n < 4; ++n) oacc[m][n] = z4;
  float mrow[2][4], lsum[2][4];
  #pragma unroll
  for (int m = 0; m < 2; ++m)
    #pragma unroll
    for (int r = 0; r < 4; ++r) { mrow[m][r] = -1e30f; lsum[m][r] = 0.f; }

  auto stage = [&](int buf, int kt) {
    int kk0 = kt * 64;
    #pragma unroll
    for (int i = 0; i < 2; ++i) {
      int c = i * 256 + wave * 64 + lane;   // 0..511
      int row = c >> 3, koct = c & 7;
      int ks = koct ^ (row & 7);
      gload_lds16(Kb + (size_t)(kk0 + row) * DD + ks * 8,
                  (char*)&Kl[buf][0] + (size_t)(i * 4 + wave) * 1024);
      gload_lds16(Vb + (size_t)row * LL + kk0 + ks * 8,
                  (char*)&Vl[buf][0] + (size_t)(i * 4 + wave) * 1024);
    }
  };

  stage(0, 0);
  int cur = 0;
  for (int kt = 0; kt < 16; ++kt) {
    if (kt + 1 < 16) {
      stage(cur ^ 1, kt + 1);
      asm volatile("s_waitcnt vmcnt(4)" ::: "memory");
    } else {
      asm volatile("s_waitcnt vmcnt(0)" ::: "memory");
    }
    __builtin_amdgcn_s_barrier();
    __builtin_amdgcn_sched_barrier(0);

    // ---- S = Q @ K^T : 32 q-rows x 64 keys per wave ----
    f32x4 sac[2][4];
    #pragma unroll
    for (int m = 0; m < 2; ++m)
      #pragma unroll
      for (int nb = 0; nb < 4; ++nb) sac[m][nb] = z4;
    __builtin_amdgcn_s_setprio(1);
    #pragma unroll
    for (int s = 0; s < 2; ++s) {
      #pragma unroll
      for (int nb = 0; nb < 4; ++nb) {
        int key = nb * 16 + lr;
        int dct = s * 4 + lg;
        short8 bk = *(const short8*)((const char*)&Kl[cur][0] + (size_t)key * 128 + ((dct ^ (key & 7)) << 4));
        sac[0][nb] = __builtin_amdgcn_mfma_f32_16x16x32_bf16(aq[0][s], bk, sac[0][nb], 0, 0, 0);
        sac[1][nb] = __builtin_amdgcn_mfma_f32_16x16x32_bf16(aq[1][s], bk, sac[1][nb], 0, 0, 0);
      }
    }
    __builtin_amdgcn_s_setprio(0);

    // ---- online softmax (lane holds key-col lr of rows m*16 + lg*4 + r) ----
    float alpha[2][4];
    #pragma unroll
    for (int m = 0; m < 2; ++m)
      #pragma unroll
      for (int r = 0; r < 4; ++r) {
        float v = fmaxf(fmaxf(sac[m][0][r], sac[m][1][r]), fmaxf(sac[m][2][r], sac[m][3][r]));
        v = fmaxf(v, __shfl_xor(v, 1));
        v = fmaxf(v, __shfl_xor(v, 2));
        v = fmaxf(v, __shfl_xor(v, 4));
        v = fmaxf(v, __shfl_xor(v, 8));
        float mn = fmaxf(mrow[m][r], v);
        alpha[m][r] = __expf(mrow[m][r] - mn);
        mrow[m][r] = mn;
      }
    float rsum[2][4];
    #pragma unroll
    for (int m = 0; m < 2; ++m)
      #pragma unroll
      for (int r = 0; r < 4; ++r) rsum[m][r] = 0.f;
    #pragma unroll
    for (int m = 0; m < 2; ++m)
      #pragma unroll
      for (int nb = 0; nb < 4; ++nb)
        #pragma unroll
        for (int r = 0; r < 4; ++r) {
          float p = __expf(sac[m][nb][r] - mrow[m][r]);
          rsum[m][r] += p;
          Pl[wave][(size_t)(m * 16 + lg * 4 + r) * 72 + nb * 16 + lr] = (u16)f2bf(p);
        }
    #pragma unroll
    for (int m = 0; m < 2; ++m)
      #pragma unroll
      for (int r = 0; r < 4; ++r) {
        float v = rsum[m][r];
        v += __shfl_xor(v, 1);
        v += __shfl_xor(v, 2);
        v += __shfl_xor(v, 4);
        v += __shfl_xor(v, 8);
        lsum[m][r] = lsum[m][r] * alpha[m][r] + v;
        #pragma unroll
        for (int nb = 0; nb < 4; ++nb) oacc[m][nb][r] *= alpha[m][r];
      }

    // ---- O += P @ V ----
    __builtin_amdgcn_s_setprio(1);
    #pragma unroll
    for (int s = 0; s < 2; ++s) {
      short8 ap0 = *(const short8*)(&Pl[wave][(size_t)lr * 72 + s * 32 + lg * 8]);
      short8 ap1 = *(const short8*)(&Pl[wave][(size_t)(16 + lr) * 72 + s * 32 + lg * 8]);
      #pragma unroll
      for (int nb = 0; nb < 4; ++nb) {
        int d = nb * 16 + lr;
        int dct = s * 4 + lg;
        short8 bv = *(const short8*)((const char*)&Vl[cur][0] + (size_t)d * 128 + ((dct ^ (d & 7)) << 4));
        oacc[0][nb] = __builtin_amdgcn_mfma_f32_16x16x32_bf16(ap0, bv, oacc[0][nb], 0, 0, 0);
        oacc[1][nb] = __builtin_amdgcn_mfma_f32_16x16x32_bf16(ap1, bv, oacc[1][nb], 0, 0, 0);
      }
    }
    __builtin_amdgcn_s_setprio(0);

    __builtin_amdgcn_s_barrier();
    cur ^= 1;
  }

  // epilogue: O /= lsum, write [B,L,C] bf16
  int b = bh >> 3, h = bh & 7;
  #pragma unroll
  for (int m = 0; m < 2; ++m) {
    float inv[4];
    #pragma unroll
    for (int r = 0; r < 4; ++r) inv[r] = 1.0f / lsum[m][r];
    #pragma unroll
    for (int nb = 0; nb < 4; ++nb)
      #pragma unroll
      for (int r = 0; r < 4; ++r) {
        int q = q0 + wave * 32 + m * 16 + lg * 4 + r;
        int col = h * 64 + nb * 16 + lr;
        Oh[(size_t)(b * LL + q) * CC + col] = (u16)f2bf(oacc[m][nb][r] * inv[r]);
      }
  }
}

// ---------------- output projection + residual ----------------
__global__ __launch_bounds__(256) void out_gemm_kernel(
    const u16* __restrict__ Oh, const u16* __restrict__ Wo_bf,
    const float* __restrict__ bo, const float* __restrict__ query,
    float* __restrict__ out) {
  __shared__ __align__(16) u16 Alds[2 * BM * BK];
  __shared__ __align__(16) u16 Blds[2 * BN * BK];
  int m0 = blockIdx.x * BM, n0 = blockIdx.y * BN;
  f32x4 acc[4][4];
  f32x4 z4 = {0.f, 0.f, 0.f, 0.f};
  #pragma unroll
  for (int m = 0; m < 4; ++m)
    #pragma unroll
    for (int n = 0; n < 4; ++n) acc[m][n] = z4;

  gemm_mainloop<CC>(Oh, Wo_bf, m0, n0, Alds, Blds, acc);

  const int lane = threadIdx.x & 63, wave = threadIdx.x >> 6;
  const int wr = wave >> 1, wc = wave & 1;
  const int lr = lane & 15, lg = lane >> 4;
  #pragma unroll
  for (int m = 0; m < 4; ++m) {
    int rowb = m0 + wr * 64 + m * 16 + lg * 4;
    #pragma unroll
    for (int n = 0; n < 4; ++n) {
      int col = n0 + wc * 64 + n * 16 + lr;
      float bias = bo[col];
      #pragma unroll
      for (int r = 0; r < 4; ++r) {
        int rw = rowb + r;
        size_t idx = (size_t)rw * CC + col;
        out[idx] = acc[m][n][r] + bias + query[idx];
      }
    }
  }
}

// ---------------- launcher ----------------
extern "C" void kernel_launch(void* const* d_in, const int* in_sizes, int n_in,
                              void* d_out, int out_size, void* d_ws, size_t ws_size,
                              hipStream_t stream) {
  (void)in_sizes; (void)n_in; (void)out_size;
  const float* query = (const float*)d_in[0];
  const float* qpos  = (const float*)d_in[1];
  const float* Wqc = (const float*)d_in[2];
  const float* bqc = (const float*)d_in[3];
  const float* Wqp = (const float*)d_in[4];
  const float* bqp = (const float*)d_in[5];
  const float* Wkc = (const float*)d_in[6];
  const float* bkc = (const float*)d_in[7];
  const float* Wkp = (const float*)d_in[8];
  const float* bkp = (const float*)d_in[9];
  const float* Wv  = (const float*)d_in[10];
  const float* bv  = (const float*)d_in[11];
  const float* Wo  = (const float*)d_in[12];
  const float* bo  = (const float*)d_in[13];

  char* ws = (char*)d_ws;
  if (ws_size < WS_END) return;

  u16*   Xcat     = (u16*)(ws + WS_XCAT);
  u16*   Wcat     = (u16*)(ws + WS_WCAT);
  u16*   Wo_bf    = (u16*)(ws + WS_WO);
  float* bias_cat = (float*)(ws + WS_BIAS);
  u16*   Qh       = (u16*)(ws + WS_QH);
  u16*   Kh       = (u16*)(ws + WS_KH);
  u16*   Vth      = (u16*)(ws + WS_VT);
  u16*   Oh       = (u16*)(ws + WS_OH);
  float* out      = (float*)d_out;

  pack_x_kernel<<<dim3(8192), dim3(256), 0, stream>>>(query, qpos, Xcat);
  pack_w_kernel<<<dim3(896), dim3(256), 0, stream>>>(Wqc, Wqp, Wkc, Wkp, Wv, Wo,
                                                     bqc, bqp, bkc, bkp, bv,
                                                     Wcat, Wo_bf, bias_cat);
  proj_gemm_kernel<<<dim3(MROWS / BM, NPROJ / BN), dim3(256), 0, stream>>>(
      Xcat, Wcat, bias_cat, Qh, Kh, Vth);
  attn_kernel<<<dim3(LL / 128, BB * HH), dim3(256), 0, stream>>>(Qh, Kh, Vth, Oh);
  out_gemm_kernel<<<dim3(MROWS / BM, CC / BN), dim3(256), 0, stream>>>(
      Oh, Wo_bf, bo, query, out);
}

// Round 3
// 210.550 us; speedup vs baseline: 1.1468x; 1.1468x over previous
//
#include <hip/hip_runtime.h>

typedef __attribute__((ext_vector_type(8))) short short8;
typedef __attribute__((ext_vector_type(4))) short short4v;
typedef __attribute__((ext_vector_type(4))) float f32x4;
typedef unsigned short u16;

#define QSCALE 0.18033688011112042f   /* 0.125 * log2(e): softmax done in exp2 domain */

#define BB 16
#define LL 1024
#define CC 512
#define HH 8
#define DD 64
#define MROWS (BB*LL)      /* 16384 */
#define KPROJ 1024
#define NPROJ 1536

#define BM 128
#define BN 128
#define BK 32

// workspace offsets (bytes). Vt aliases Xcat (Xcat dead after proj_gemm).
#define WS_XCAT   0ull
#define WS_WCAT   (WS_XCAT + (size_t)MROWS*KPROJ*2)
#define WS_WO     (WS_WCAT + (size_t)NPROJ*KPROJ*2)
#define WS_BIAS   (WS_WO   + (size_t)CC*CC*2)
#define WS_QH     (WS_BIAS + 8192)
#define WS_KH     (WS_QH + (size_t)MROWS*CC*2)
#define WS_VH     (WS_KH + (size_t)MROWS*CC*2)
#define WS_OH     (WS_VH + (size_t)MROWS*CC*2)
#define WS_END    (WS_OH + (size_t)MROWS*CC*2)
#define WS_VT     WS_XCAT

__device__ inline short f2bf(float f) {
  unsigned u = __builtin_bit_cast(unsigned, f);
  u = (u + 0x7FFFu + ((u >> 16) & 1u)) >> 16;
  return (short)u;
}

__device__ inline short8 pack8(const float* src) {
  float4 a = ((const float4*)src)[0];
  float4 b = ((const float4*)src)[1];
  short8 v;
  v[0]=f2bf(a.x); v[1]=f2bf(a.y); v[2]=f2bf(a.z); v[3]=f2bf(a.w);
  v[4]=f2bf(b.x); v[5]=f2bf(b.y); v[6]=f2bf(b.z); v[7]=f2bf(b.w);
  return v;
}

__device__ inline void gload_lds16(const u16* g, char* lds_byte) {
  __builtin_amdgcn_global_load_lds(
      (const __attribute__((address_space(1))) unsigned int*)g,
      (__attribute__((address_space(3))) unsigned int*)lds_byte,
      16, 0, 0);
}

// ---------------- pack kernels ----------------

__global__ __launch_bounds__(256) void pack_x_kernel(
    const float* __restrict__ q, const float* __restrict__ qp, u16* __restrict__ xcat) {
  int o = blockIdx.x * 256 + threadIdx.x;
  int row = o >> 7;
  int kk  = (o & 127) << 3;
  const float* src = (kk < 512) ? (q + (size_t)row * 512 + kk)
                                : (qp + (size_t)row * 512 + (kk - 512));
  short8 v = pack8(src);
  *(short8*)(xcat + (size_t)row * KPROJ + kk) = v;
}

__global__ __launch_bounds__(256) void pack_w_kernel(
    const float* __restrict__ Wqc, const float* __restrict__ Wqp,
    const float* __restrict__ Wkc, const float* __restrict__ Wkp,
    const float* __restrict__ Wv,  const float* __restrict__ Wo,
    const float* __restrict__ bqc, const float* __restrict__ bqp,
    const float* __restrict__ bkc, const float* __restrict__ bkp,
    const float* __restrict__ bv,
    u16* __restrict__ wcat, u16* __restrict__ wo_bf, float* __restrict__ bias_cat) {
  int o = blockIdx.x * 256 + threadIdx.x;
  if (o < 196608) {
    int j = o >> 7;
    int kk = (o & 127) << 3;
    const float* src = nullptr;
    if (j < 512)        src = (kk < 512) ? Wqc + (size_t)j * 512 + kk : Wqp + (size_t)j * 512 + (kk - 512);
    else if (j < 1024) { int jj = j - 512;  src = (kk < 512) ? Wkc + (size_t)jj * 512 + kk : Wkp + (size_t)jj * 512 + (kk - 512); }
    else               { int jj = j - 1024; src = (kk < 512) ? Wv  + (size_t)jj * 512 + kk : nullptr; }
    short8 v = {0,0,0,0,0,0,0,0};
    if (src) v = pack8(src);
    *(short8*)(wcat + (size_t)j * KPROJ + kk) = v;
  } else if (o < 229376) {
    int o2 = o - 196608;
    int j = o2 >> 6;
    int kk = (o2 & 63) << 3;
    short8 v = pack8(Wo + (size_t)j * 512 + kk);
    *(short8*)(wo_bf + (size_t)j * 512 + kk) = v;
  }
  if (o < 1536) {
    float v;
    if (o < 512)       v = bqc[o] + bqp[o];
    else if (o < 1024) v = bkc[o - 512] + bkp[o - 512];
    else               v = bv[o - 1024];
    bias_cat[o] = v;
  }
}

// ---------------- GEMM core ----------------
template <int KDIM>
__device__ inline void gemm_mainloop(const u16* __restrict__ A, const u16* __restrict__ Bw,
                                     int m0, int n0,
                                     u16* Alds, u16* Blds,
                                     f32x4 (&acc)[4][4]) {
  const int tid = threadIdx.x;
  const int lane = tid & 63, wave = tid >> 6;
  const int wr = wave >> 1, wc = wave & 1;
  const int lr = lane & 15, lg = lane >> 4;

  auto stage = [&](int buf, int t) {
    int k0 = t * BK;
    #pragma unroll
    for (int i = 0; i < 2; ++i) {
      int c = (i * 4 + wave) * 64 + lane;
      int row = c >> 2, koct = c & 3;
      char* ldsbaseA = (char*)Alds + (size_t)buf * (BM * BK * 2) + (size_t)(i * 4 + wave) * 1024;
      char* ldsbaseB = (char*)Blds + (size_t)buf * (BN * BK * 2) + (size_t)(i * 4 + wave) * 1024;
      gload_lds16(A  + (size_t)(m0 + row) * KDIM + k0 + koct * 8, ldsbaseA);
      gload_lds16(Bw + (size_t)(n0 + row) * KDIM + k0 + koct * 8, ldsbaseB);
    }
  };

  stage(0, 0);
  constexpr int NT = KDIM / BK;
  int cur = 0;
  for (int t = 0; t < NT; ++t) {
    __syncthreads();
    if (t + 1 < NT) stage(cur ^ 1, t + 1);
    const u16* Ab = Alds + (size_t)cur * (BM * BK);
    const u16* Bb = Blds + (size_t)cur * (BN * BK);
    short8 af[4], bfr[4];
    #pragma unroll
    for (int m = 0; m < 4; ++m)
      af[m] = *(const short8*)(Ab + (size_t)(wr * 64 + m * 16 + lr) * BK + lg * 8);
    #pragma unroll
    for (int n = 0; n < 4; ++n)
      bfr[n] = *(const short8*)(Bb + (size_t)(wc * 64 + n * 16 + lr) * BK + lg * 8);
    #pragma unroll
    for (int m = 0; m < 4; ++m)
      #pragma unroll
      for (int n = 0; n < 4; ++n)
        acc[m][n] = __builtin_amdgcn_mfma_f32_16x16x32_bf16(af[m], bfr[n], acc[m][n], 0, 0, 0);
    cur ^= 1;
  }
}

// ---------------- projection GEMM ----------------
__global__ __launch_bounds__(256) void proj_gemm_kernel(
    const u16* __restrict__ Xcat, const u16* __restrict__ Wcat,
    const float* __restrict__ bias_cat,
    u16* __restrict__ Qh, u16* __restrict__ Kh, u16* __restrict__ Vh) {
  __shared__ __align__(16) u16 Alds[2 * BM * BK];
  __shared__ __align__(16) u16 Blds[2 * BN * BK];
  int m0 = blockIdx.x * BM, n0 = blockIdx.y * BN;
  f32x4 acc[4][4];
  f32x4 z4 = {0.f, 0.f, 0.f, 0.f};
  #pragma unroll
  for (int m = 0; m < 4; ++m)
    #pragma unroll
    for (int n = 0; n < 4; ++n) acc[m][n] = z4;

  gemm_mainloop<KPROJ>(Xcat, Wcat, m0, n0, Alds, Blds, acc);

  const int lane = threadIdx.x & 63, wave = threadIdx.x >> 6;
  const int wr = wave >> 1, wc = wave & 1;
  const int lr = lane & 15, lg = lane >> 4;
  #pragma unroll
  for (int m = 0; m < 4; ++m) {
    int rowb = m0 + wr * 64 + m * 16 + lg * 4;
    #pragma unroll
    for (int n = 0; n < 4; ++n) {
      int col = n0 + wc * 64 + n * 16 + lr;
      float bias = bias_cat[col];
      int sec = col >> 9;
      int cj = col & 511;
      int h = cj >> 6, d = cj & 63;
      #pragma unroll
      for (int r = 0; r < 4; ++r) {
        int rw = rowb + r;
        int b = rw >> 10, l = rw & 1023;
        float v = acc[m][n][r] + bias;
        size_t idx = ((size_t)(b * HH + h) * LL + l) * DD + d;
        if (sec == 0)      Qh[idx] = (u16)f2bf(v * QSCALE);
        else if (sec == 1) Kh[idx] = (u16)f2bf(v);
        else               Vh[idx] = (u16)f2bf(v);
      }
    }
  }
}

// ---------------- V transpose: Vh[bh][l][d] -> Vt[bh][d][l] ----------------
__global__ __launch_bounds__(256) void vtrans_kernel(
    const u16* __restrict__ Vh, u16* __restrict__ Vt) {
  __shared__ u16 T[64][72];
  int bh = blockIdx.y;
  int l0 = blockIdx.x * 64;
  int t = threadIdx.x;
  const u16* src = Vh + (size_t)bh * LL * DD;
  {
    int l = t >> 2, dq = (t & 3) * 16;
    short8 v0 = *(const short8*)(src + (size_t)(l0 + l) * DD + dq);
    short8 v1 = *(const short8*)(src + (size_t)(l0 + l) * DD + dq + 8);
    #pragma unroll
    for (int j = 0; j < 8; ++j) T[dq + j][l] = (u16)v0[j];
    #pragma unroll
    for (int j = 0; j < 8; ++j) T[dq + 8 + j][l] = (u16)v1[j];
  }
  __syncthreads();
  {
    int d = t >> 2, lq = (t & 3) * 16;
    u16* dst = Vt + (size_t)bh * DD * LL + (size_t)d * LL + l0 + lq;
    *(short8*)dst = *(const short8*)&T[d][lq];
    *(short8*)(dst + 8) = *(const short8*)&T[d][lq + 8];
  }
}

// ---------------- flash attention (transposed-softmax structure) ----------------
// grid: (L/128, B*H). 4 waves x 32 q-rows. KV tiles of 64.
// S^T = mfma(K,Q): lane holds q=lr, 16 keys in-register -> lane-local softmax.
// P^T->P transpose through packed-u32 per-wave LDS. O^T = mfma(V,P): rescale lane-local.
__global__ __launch_bounds__(256, 3) void attn_kernel(
    const u16* __restrict__ Qh, const u16* __restrict__ Kh,
    const u16* __restrict__ Vt, u16* __restrict__ Oh) {
  __shared__ __align__(16) u16 Kl[2][64 * 64];
  __shared__ __align__(16) u16 Vl[2][64 * 64];
  __shared__ __align__(16) unsigned int Pp[4][2][512];   // [wave][qhalf][lr*32 + ent*2 + i]

  const int tid = threadIdx.x;
  const int lane = tid & 63, wave = tid >> 6;
  const int lr = lane & 15, lg = lane >> 4;
  const int sw = (lr & 7) * 2;           // even XOR swizzle: preserves b64/b128 grouping
  const int q0 = blockIdx.x * 128;
  const int bh = blockIdx.y;

  const u16* Qb = Qh + (size_t)bh * LL * DD;
  const u16* Kb = Kh + (size_t)bh * LL * DD;
  const u16* Vb = Vt + (size_t)bh * DD * LL;

  // Q fragments (used as SECOND mfma operand): q-row = q0 + wave*32 + m*16 + lr
  short8 aq[2][2];
  #pragma unroll
  for (int m = 0; m < 2; ++m)
    #pragma unroll
    for (int s = 0; s < 2; ++s)
      aq[m][s] = *(const short8*)(Qb + (size_t)(q0 + wave * 32 + m * 16 + lr) * DD + s * 32 + lg * 8);

  f32x4 z4 = {0.f, 0.f, 0.f, 0.f};
  f32x4 oaccT[2][4];                      // O^T: d = db*16 + lg*4 + r, q = m*16 + lr
  #pragma unroll
  for (int m = 0; m < 2; ++m)
    #pragma unroll
    for (int db = 0; db < 4; ++db) oaccT[m][db] = z4;
  float mrow[2] = {-3e38f, -3e38f}, lsum[2] = {0.f, 0.f};

  auto stage = [&](int buf, int kt) {
    int kk0 = kt * 64;
    #pragma unroll
    for (int i = 0; i < 2; ++i) {
      int c = i * 256 + wave * 64 + lane;
      int row = c >> 3, koct = c & 7;
      int ks = koct ^ (row & 7);
      gload_lds16(Kb + (size_t)(kk0 + row) * DD + ks * 8,
                  (char*)&Kl[buf][0] + (size_t)(i * 4 + wave) * 1024);
      gload_lds16(Vb + (size_t)row * LL + kk0 + ks * 8,
                  (char*)&Vl[buf][0] + (size_t)(i * 4 + wave) * 1024);
    }
  };

  stage(0, 0);
  int cur = 0;
  for (int kt = 0; kt < 16; ++kt) {
    if (kt + 1 < 16) {
      stage(cur ^ 1, kt + 1);
      asm volatile("s_waitcnt vmcnt(4)" ::: "memory");
    } else {
      asm volatile("s_waitcnt vmcnt(0)" ::: "memory");
    }
    __builtin_amdgcn_s_barrier();
    __builtin_amdgcn_sched_barrier(0);

    // ---- S^T = K @ Q^T : lane (lr,lg) -> key = kb*16 + lg*4 + r, q = m*16 + lr ----
    f32x4 ps[2][4];
    #pragma unroll
    for (int m = 0; m < 2; ++m)
      #pragma unroll
      for (int kb = 0; kb < 4; ++kb) ps[m][kb] = z4;
    __builtin_amdgcn_s_setprio(1);
    #pragma unroll
    for (int s = 0; s < 2; ++s) {
      #pragma unroll
      for (int kb = 0; kb < 4; ++kb) {
        int key = kb * 16 + lr;
        int dct = s * 4 + lg;
        short8 ka = *(const short8*)((const char*)&Kl[cur][0] + (size_t)key * 128 + ((dct ^ (key & 7)) << 4));
        ps[0][kb] = __builtin_amdgcn_mfma_f32_16x16x32_bf16(ka, aq[0][s], ps[0][kb], 0, 0, 0);
        ps[1][kb] = __builtin_amdgcn_mfma_f32_16x16x32_bf16(ka, aq[1][s], ps[1][kb], 0, 0, 0);
      }
    }
    __builtin_amdgcn_s_setprio(0);

    // ---- lane-local online softmax (exp2 domain) ----
    #pragma unroll
    for (int m = 0; m < 2; ++m) {
      float a0 = fmaxf(fmaxf(ps[m][0][0], ps[m][0][1]), fmaxf(ps[m][0][2], ps[m][0][3]));
      float a1 = fmaxf(fmaxf(ps[m][1][0], ps[m][1][1]), fmaxf(ps[m][1][2], ps[m][1][3]));
      float a2 = fmaxf(fmaxf(ps[m][2][0], ps[m][2][1]), fmaxf(ps[m][2][2], ps[m][2][3]));
      float a3 = fmaxf(fmaxf(ps[m][3][0], ps[m][3][1]), fmaxf(ps[m][3][2], ps[m][3][3]));
      float v = fmaxf(fmaxf(a0, a1), fmaxf(a2, a3));
      v = fmaxf(v, __shfl_xor(v, 16));
      v = fmaxf(v, __shfl_xor(v, 32));
      float mn = fmaxf(mrow[m], v);
      float alpha = exp2f(mrow[m] - mn);
      mrow[m] = mn;
      float rs = 0.f;
      #pragma unroll
      for (int kb = 0; kb < 4; ++kb)
        #pragma unroll
        for (int r = 0; r < 4; ++r) {
          float p = exp2f(ps[m][kb][r] - mn);
          ps[m][kb][r] = p;
          rs += p;
        }
      rs += __shfl_xor(rs, 16);
      rs += __shfl_xor(rs, 32);
      lsum[m] = lsum[m] * alpha + rs;
      #pragma unroll
      for (int db = 0; db < 4; ++db)
        #pragma unroll
        for (int r = 0; r < 4; ++r) oaccT[m][db][r] *= alpha;
      // pack P^T pairs -> per-wave LDS (transpose to A/B-frag layout)
      #pragma unroll
      for (int kb = 0; kb < 4; ++kb) {
        unsigned b0 = __builtin_bit_cast(unsigned, ps[m][kb][0]);
        unsigned b1 = __builtin_bit_cast(unsigned, ps[m][kb][1]);
        unsigned b2 = __builtin_bit_cast(unsigned, ps[m][kb][2]);
        unsigned b3 = __builtin_bit_cast(unsigned, ps[m][kb][3]);
        unsigned lo = ((b0 + 0x8000u) >> 16) | ((b1 + 0x8000u) & 0xFFFF0000u);
        unsigned hi = ((b2 + 0x8000u) >> 16) | ((b3 + 0x8000u) & 0xFFFF0000u);
        int ent = ((kb * 4 + lg) ^ sw) * 2;
        uint2 w; w.x = lo; w.y = hi;
        *(uint2*)&Pp[wave][m][lr * 32 + ent] = w;
      }
    }

    // ---- O^T += V^T @ P : lane -> d = db*16 + lg*4 + r, q = m*16 + lr ----
    __builtin_amdgcn_s_setprio(1);
    #pragma unroll
    for (int s = 0; s < 2; ++s) {
      short8 ap[2];
      #pragma unroll
      for (int m = 0; m < 2; ++m) {
        int val0 = s * 8 + (lg >> 1) * 4 + (lg & 1) * 2;
        uint4 pw = *(const uint4*)&Pp[wave][m][lr * 32 + ((val0 ^ sw) * 2)];
        ap[m] = __builtin_bit_cast(short8, pw);
      }
      #pragma unroll
      for (int db = 0; db < 4; ++db) {
        int d = db * 16 + lr;
        int kct = s * 4 + lg;
        short8 bv = *(const short8*)((const char*)&Vl[cur][0] + (size_t)d * 128 + ((kct ^ (d & 7)) << 4));
        oaccT[0][db] = __builtin_amdgcn_mfma_f32_16x16x32_bf16(bv, ap[0], oaccT[0][db], 0, 0, 0);
        oaccT[1][db] = __builtin_amdgcn_mfma_f32_16x16x32_bf16(bv, ap[1], oaccT[1][db], 0, 0, 0);
      }
    }
    __builtin_amdgcn_s_setprio(0);

    __builtin_amdgcn_s_barrier();
    cur ^= 1;
  }

  // epilogue: O = O^T^T / lsum -> [B,L,C] bf16, 8B stores (4 consecutive d per reg quad)
  int b = bh >> 3, h = bh & 7;
  #pragma unroll
  for (int m = 0; m < 2; ++m) {
    float inv = 1.0f / lsum[m];
    int q = q0 + wave * 32 + m * 16 + lr;
    #pragma unroll
    for (int db = 0; db < 4; ++db) {
      int d0 = db * 16 + lg * 4;
      short4v o;
      #pragma unroll
      for (int r = 0; r < 4; ++r) o[r] = f2bf(oaccT[m][db][r] * inv);
      *(short4v*)&Oh[(size_t)(b * LL + q) * CC + h * 64 + d0] = o;
    }
  }
}

// ---------------- output projection + residual ----------------
__global__ __launch_bounds__(256) void out_gemm_kernel(
    const u16* __restrict__ Oh, const u16* __restrict__ Wo_bf,
    const float* __restrict__ bo, const float* __restrict__ query,
    float* __restrict__ out) {
  __shared__ __align__(16) u16 Alds[2 * BM * BK];
  __shared__ __align__(16) u16 Blds[2 * BN * BK];
  int m0 = blockIdx.x * BM, n0 = blockIdx.y * BN;
  f32x4 acc[4][4];
  f32x4 z4 = {0.f, 0.f, 0.f, 0.f};
  #pragma unroll
  for (int m = 0; m < 4; ++m)
    #pragma unroll
    for (int n = 0; n < 4; ++n) acc[m][n] = z4;

  gemm_mainloop<CC>(Oh, Wo_bf, m0, n0, Alds, Blds, acc);

  const int lane = threadIdx.x & 63, wave = threadIdx.x >> 6;
  const int wr = wave >> 1, wc = wave & 1;
  const int lr = lane & 15, lg = lane >> 4;
  #pragma unroll
  for (int m = 0; m < 4; ++m) {
    int rowb = m0 + wr * 64 + m * 16 + lg * 4;
    #pragma unroll
    for (int n = 0; n < 4; ++n) {
      int col = n0 + wc * 64 + n * 16 + lr;
      float bias = bo[col];
      #pragma unroll
      for (int r = 0; r < 4; ++r) {
        int rw = rowb + r;
        size_t idx = (size_t)rw * CC + col;
        out[idx] = acc[m][n][r] + bias + query[idx];
      }
    }
  }
}

// ---------------- launcher ----------------
extern "C" void kernel_launch(void* const* d_in, const int* in_sizes, int n_in,
                              void* d_out, int out_size, void* d_ws, size_t ws_size,
                              hipStream_t stream) {
  (void)in_sizes; (void)n_in; (void)out_size;
  const float* query = (const float*)d_in[0];
  const float* qpos  = (const float*)d_in[1];
  const float* Wqc = (const float*)d_in[2];
  const float* bqc = (const float*)d_in[3];
  const float* Wqp = (const float*)d_in[4];
  const float* bqp = (const float*)d_in[5];
  const float* Wkc = (const float*)d_in[6];
  const float* bkc = (const float*)d_in[7];
  const float* Wkp = (const float*)d_in[8];
  const float* bkp = (const float*)d_in[9];
  const float* Wv  = (const float*)d_in[10];
  const float* bv  = (const float*)d_in[11];
  const float* Wo  = (const float*)d_in[12];
  const float* bo  = (const float*)d_in[13];

  char* ws = (char*)d_ws;
  if (ws_size < WS_END) return;

  u16*   Xcat     = (u16*)(ws + WS_XCAT);
  u16*   Wcat     = (u16*)(ws + WS_WCAT);
  u16*   Wo_bf    = (u16*)(ws + WS_WO);
  float* bias_cat = (float*)(ws + WS_BIAS);
  u16*   Qh       = (u16*)(ws + WS_QH);
  u16*   Kh       = (u16*)(ws + WS_KH);
  u16*   Vh       = (u16*)(ws + WS_VH);
  u16*   Oh       = (u16*)(ws + WS_OH);
  u16*   Vtr      = (u16*)(ws + WS_VT);   // aliases Xcat (dead after proj)
  float* out      = (float*)d_out;

  pack_x_kernel<<<dim3(8192), dim3(256), 0, stream>>>(query, qpos, Xcat);
  pack_w_kernel<<<dim3(896), dim3(256), 0, stream>>>(Wqc, Wqp, Wkc, Wkp, Wv, Wo,
                                                     bqc, bqp, bkc, bkp, bv,
                                                     Wcat, Wo_bf, bias_cat);
  proj_gemm_kernel<<<dim3(MROWS / BM, NPROJ / BN), dim3(256), 0, stream>>>(
      Xcat, Wcat, bias_cat, Qh, Kh, Vh);
  vtrans_kernel<<<dim3(LL / 64, BB * HH), dim3(256), 0, stream>>>(Vh, Vtr);
  attn_kernel<<<dim3(LL / 128, BB * HH), dim3(256), 0, stream>>>(Qh, Kh, Vtr, Oh);
  out_gemm_kernel<<<dim3(MROWS / BM, CC / BN), dim3(256), 0, stream>>>(
      Oh, Wo_bf, bo, query, out);
}

// Round 4
// 206.195 us; speedup vs baseline: 1.1710x; 1.0211x over previous
//
#include <hip/hip_runtime.h>

typedef __attribute__((ext_vector_type(8))) short short8;
typedef __attribute__((ext_vector_type(4))) short short4v;
typedef __attribute__((ext_vector_type(4))) float f32x4;
typedef unsigned short u16;

#define QSCALE 0.18033688011112042f   /* 0.125 * log2(e): softmax done in exp2 domain */

#define BB 16
#define LL 1024
#define CC 512
#define HH 8
#define DD 64
#define MROWS (BB*LL)      /* 16384 */
#define KPROJ 1024
#define NPROJ 1536

#define BM 128
#define BN 128
#define BK 32

// workspace offsets (bytes). Vt aliases Xcat (Xcat dead after proj_gemm).
#define WS_XCAT   0ull
#define WS_WCAT   (WS_XCAT + (size_t)MROWS*KPROJ*2)
#define WS_WO     (WS_WCAT + (size_t)NPROJ*KPROJ*2)
#define WS_BIAS   (WS_WO   + (size_t)CC*CC*2)
#define WS_QH     (WS_BIAS + 8192)
#define WS_KH     (WS_QH + (size_t)MROWS*CC*2)
#define WS_VH     (WS_KH + (size_t)MROWS*CC*2)
#define WS_OH     (WS_VH + (size_t)MROWS*CC*2)
#define WS_END    (WS_OH + (size_t)MROWS*CC*2)
#define WS_VT     WS_XCAT

__device__ inline short f2bf(float f) {
  unsigned u = __builtin_bit_cast(unsigned, f);
  u = (u + 0x7FFFu + ((u >> 16) & 1u)) >> 16;
  return (short)u;
}

__device__ inline short8 pack8(const float* src) {
  float4 a = ((const float4*)src)[0];
  float4 b = ((const float4*)src)[1];
  short8 v;
  v[0]=f2bf(a.x); v[1]=f2bf(a.y); v[2]=f2bf(a.z); v[3]=f2bf(a.w);
  v[4]=f2bf(b.x); v[5]=f2bf(b.y); v[6]=f2bf(b.z); v[7]=f2bf(b.w);
  return v;
}

__device__ inline void gload_lds16(const u16* g, char* lds_byte) {
  __builtin_amdgcn_global_load_lds(
      (const __attribute__((address_space(1))) unsigned int*)g,
      (__attribute__((address_space(3))) unsigned int*)lds_byte,
      16, 0, 0);
}

// ---------------- pack kernels ----------------

__global__ __launch_bounds__(256) void pack_x_kernel(
    const float* __restrict__ q, const float* __restrict__ qp, u16* __restrict__ xcat) {
  int o = blockIdx.x * 256 + threadIdx.x;
  int row = o >> 7;
  int kk  = (o & 127) << 3;
  const float* src = (kk < 512) ? (q + (size_t)row * 512 + kk)
                                : (qp + (size_t)row * 512 + (kk - 512));
  short8 v = pack8(src);
  *(short8*)(xcat + (size_t)row * KPROJ + kk) = v;
}

__global__ __launch_bounds__(256) void pack_w_kernel(
    const float* __restrict__ Wqc, const float* __restrict__ Wqp,
    const float* __restrict__ Wkc, const float* __restrict__ Wkp,
    const float* __restrict__ Wv,  const float* __restrict__ Wo,
    const float* __restrict__ bqc, const float* __restrict__ bqp,
    const float* __restrict__ bkc, const float* __restrict__ bkp,
    const float* __restrict__ bv,
    u16* __restrict__ wcat, u16* __restrict__ wo_bf, float* __restrict__ bias_cat) {
  int o = blockIdx.x * 256 + threadIdx.x;
  if (o < 196608) {
    int j = o >> 7;
    int kk = (o & 127) << 3;
    const float* src = nullptr;
    if (j < 512)        src = (kk < 512) ? Wqc + (size_t)j * 512 + kk : Wqp + (size_t)j * 512 + (kk - 512);
    else if (j < 1024) { int jj = j - 512;  src = (kk < 512) ? Wkc + (size_t)jj * 512 + kk : Wkp + (size_t)jj * 512 + (kk - 512); }
    else               { int jj = j - 1024; src = (kk < 512) ? Wv  + (size_t)jj * 512 + kk : nullptr; }
    short8 v = {0,0,0,0,0,0,0,0};
    if (src) v = pack8(src);
    *(short8*)(wcat + (size_t)j * KPROJ + kk) = v;
  } else if (o < 229376) {
    int o2 = o - 196608;
    int j = o2 >> 6;
    int kk = (o2 & 63) << 3;
    short8 v = pack8(Wo + (size_t)j * 512 + kk);
    *(short8*)(wo_bf + (size_t)j * 512 + kk) = v;
  }
  if (o < 1536) {
    float v;
    if (o < 512)       v = bqc[o] + bqp[o];
    else if (o < 1024) v = bkc[o - 512] + bkp[o - 512];
    else               v = bv[o - 1024];
    bias_cat[o] = v;
  }
}

// ---------------- legacy 128x128 GEMM core (out_gemm) ----------------
template <int KDIM>
__device__ inline void gemm_mainloop(const u16* __restrict__ A, const u16* __restrict__ Bw,
                                     int m0, int n0,
                                     u16* Alds, u16* Blds,
                                     f32x4 (&acc)[4][4]) {
  const int tid = threadIdx.x;
  const int lane = tid & 63, wave = tid >> 6;
  const int wr = wave >> 1, wc = wave & 1;
  const int lr = lane & 15, lg = lane >> 4;

  auto stage = [&](int buf, int t) {
    int k0 = t * BK;
    #pragma unroll
    for (int i = 0; i < 2; ++i) {
      int c = (i * 4 + wave) * 64 + lane;
      int row = c >> 2, koct = c & 3;
      char* ldsbaseA = (char*)Alds + (size_t)buf * (BM * BK * 2) + (size_t)(i * 4 + wave) * 1024;
      char* ldsbaseB = (char*)Blds + (size_t)buf * (BN * BK * 2) + (size_t)(i * 4 + wave) * 1024;
      gload_lds16(A  + (size_t)(m0 + row) * KDIM + k0 + koct * 8, ldsbaseA);
      gload_lds16(Bw + (size_t)(n0 + row) * KDIM + k0 + koct * 8, ldsbaseB);
    }
  };

  stage(0, 0);
  constexpr int NT = KDIM / BK;
  int cur = 0;
  for (int t = 0; t < NT; ++t) {
    __syncthreads();
    if (t + 1 < NT) stage(cur ^ 1, t + 1);
    const u16* Ab = Alds + (size_t)cur * (BM * BK);
    const u16* Bb = Blds + (size_t)cur * (BN * BK);
    short8 af[4], bfr[4];
    #pragma unroll
    for (int m = 0; m < 4; ++m)
      af[m] = *(const short8*)(Ab + (size_t)(wr * 64 + m * 16 + lr) * BK + lg * 8);
    #pragma unroll
    for (int n = 0; n < 4; ++n)
      bfr[n] = *(const short8*)(Bb + (size_t)(wc * 64 + n * 16 + lr) * BK + lg * 8);
    #pragma unroll
    for (int m = 0; m < 4; ++m)
      #pragma unroll
      for (int n = 0; n < 4; ++n)
        acc[m][n] = __builtin_amdgcn_mfma_f32_16x16x32_bf16(af[m], bfr[n], acc[m][n], 0, 0, 0);
    cur ^= 1;
  }
}

// ---------------- projection GEMM: 256x256 tile, BK=64, 8 waves, 8-phase ----------------
// LDS per buf: [A0 | A1 | B0 | B1], each half 128 rows x 64 k = 8192 elems (16KB).
// Staged with source-side XOR swizzle chunk_col ^= (row&7); conflict-free ds_read_b128.
// Operands swapped in MFMA (W as A-operand) so each lane holds 4 consecutive out-cols.
__global__ __launch_bounds__(512, 2) void proj_gemm_kernel(
    const u16* __restrict__ Xcat, const u16* __restrict__ Wcat,
    const float* __restrict__ bias_cat,
    u16* __restrict__ Qh, u16* __restrict__ Kh, u16* __restrict__ Vh) {
  __shared__ __align__(16) u16 lds[2 * 32768];   // 128 KB

  // bijective XCD swizzle (384 blocks, 384 % 8 == 0)
  int id0 = blockIdx.x;
  int swz = (id0 & 7) * 48 + (id0 >> 3);
  int bx = swz / 6, by = swz % 6;
  const int m0 = bx * 256, n0 = by * 256;

  const int tid = threadIdx.x;
  const int lane = tid & 63, wave = tid >> 6;
  const int wr = wave >> 2, wc = wave & 3;     // 2 M-wave-groups x 4 N-wave-groups
  const int lr = lane & 15, lg = lane >> 4;

  // stage one 16KB half-tile: unit u = {0:A-rows 0-127, 1:A-rows 128-255, 2:B-rows 0-127, 3:B-rows 128-255}
  auto stage_unit = [&](int buf, int u, int k0) {
    const u16* base = (u < 2) ? (Xcat + (size_t)(m0 + u * 128) * KPROJ + k0)
                              : (Wcat + (size_t)(n0 + (u - 2) * 128) * KPROJ + k0);
    #pragma unroll
    for (int i = 0; i < 2; ++i) {
      int s = i * 512 + tid;                   // chunk slot 0..1023
      int row = s >> 3, col = s & 7;
      int colp = col ^ (row & 7);              // inverse swizzle on SOURCE, linear dest
      gload_lds16(base + (size_t)row * KPROJ + colp * 8,
                  (char*)lds + ((size_t)buf * 32768 + (size_t)u * 8192) * 2
                             + (size_t)(i * 512 + wave * 64) * 16);
    }
  };

  // swizzled fragment reads
  auto rdW = [&](int buf, int nf, int ks) {
    int rowl = (wc & 1) * 64 + nf * 16 + lr;
    int chunk = (ks * 4 + lg) ^ (rowl & 7);
    return *(const short8*)(lds + (size_t)buf * 32768 + (size_t)(2 + (wc >> 1)) * 8192
                            + (size_t)rowl * 64 + chunk * 8);
  };
  auto rdX = [&](int buf, int mf, int ks) {
    int rowl = mf * 16 + lr;
    int chunk = (ks * 4 + lg) ^ (rowl & 7);
    return *(const short8*)(lds + (size_t)buf * 32768 + (size_t)wr * 8192
                            + (size_t)rowl * 64 + chunk * 8);
  };

  f32x4 acc[8][4];
  f32x4 z4 = {0.f, 0.f, 0.f, 0.f};
  #pragma unroll
  for (int mf = 0; mf < 8; ++mf)
    #pragma unroll
    for (int nf = 0; nf < 4; ++nf) acc[mf][nf] = z4;

  // prologue: stage K-tile 0 into buf 0, drain, barrier
  #pragma unroll
  for (int u = 0; u < 4; ++u) stage_unit(0, u, 0);
  asm volatile("s_waitcnt vmcnt(0)" ::: "memory");
  __builtin_amdgcn_s_barrier();
  __builtin_amdgcn_sched_barrier(0);

  short8 wfr[4][2];
  constexpr int NT = KPROJ / 64;   // 16 K-tiles
  for (int kt = 0; kt < NT; ++kt) {
    const int b = kt & 1;
    const bool pf = (kt + 1 < NT);
    #pragma unroll
    for (int p = 0; p < 4; ++p) {
      // ds-reads for this phase (B-frags once per tile, held in regs)
      if (p == 0) {
        #pragma unroll
        for (int nf = 0; nf < 4; ++nf)
          #pragma unroll
          for (int ks = 0; ks < 2; ++ks) wfr[nf][ks] = rdW(b, nf, ks);
      }
      short8 xf[2][2];
      #pragma unroll
      for (int mm = 0; mm < 2; ++mm)
        #pragma unroll
        for (int ks = 0; ks < 2; ++ks) xf[mm][ks] = rdX(b, p * 2 + mm, ks);
      // prefetch one half-tile of tile kt+1 into the dead buffer
      if (pf) stage_unit(b ^ 1, p, (kt + 1) * 64);
      __builtin_amdgcn_s_barrier();
      __builtin_amdgcn_sched_barrier(0);
      __builtin_amdgcn_s_setprio(1);
      #pragma unroll
      for (int mm = 0; mm < 2; ++mm)
        #pragma unroll
        for (int nf = 0; nf < 4; ++nf)
          #pragma unroll
          for (int ks = 0; ks < 2; ++ks)
            acc[p * 2 + mm][nf] = __builtin_amdgcn_mfma_f32_16x16x32_bf16(
                wfr[nf][ks], xf[mm][ks], acc[p * 2 + mm][nf], 0, 0, 0);
      __builtin_amdgcn_s_setprio(0);
      if (p == 3 && pf) asm volatile("s_waitcnt vmcnt(0)" ::: "memory");
      __builtin_amdgcn_s_barrier();
      __builtin_amdgcn_sched_barrier(0);
    }
  }

  // epilogue: lane frag (mf,nf) -> out rows l = m0+wr*128+mf*16+lr (one l),
  // cols c = n0+wc*64+nf*16+lg*4 .. +3 (consecutive) -> 8B stores
  const int cbase = n0 + wc * 64 + lg * 4;
  #pragma unroll
  for (int mf = 0; mf < 8; ++mf) {
    int lglob = m0 + wr * 128 + mf * 16 + lr;
    int bidx = lglob >> 10, lrow = lglob & 1023;
    #pragma unroll
    for (int nf = 0; nf < 4; ++nf) {
      int c = cbase + nf * 16;
      float4 bb = *(const float4*)&bias_cat[c];
      int sec = c >> 9, cj = c & 511;
      int h = cj >> 6, d0 = cj & 63;
      size_t idx = ((size_t)(bidx * HH + h) * LL + lrow) * DD + d0;
      float v0 = acc[mf][nf][0] + bb.x;
      float v1 = acc[mf][nf][1] + bb.y;
      float v2 = acc[mf][nf][2] + bb.z;
      float v3 = acc[mf][nf][3] + bb.w;
      if (sec == 0) { v0 *= QSCALE; v1 *= QSCALE; v2 *= QSCALE; v3 *= QSCALE; }
      short4v o;
      o[0] = f2bf(v0); o[1] = f2bf(v1); o[2] = f2bf(v2); o[3] = f2bf(v3);
      u16* dst = (sec == 0) ? Qh : (sec == 1) ? Kh : Vh;
      *(short4v*)&dst[idx] = o;
    }
  }
}

// ---------------- V transpose: Vh[bh][l][d] -> Vt[bh][d][l] ----------------
__global__ __launch_bounds__(256) void vtrans_kernel(
    const u16* __restrict__ Vh, u16* __restrict__ Vt) {
  __shared__ u16 T[64][72];
  int bh = blockIdx.y;
  int l0 = blockIdx.x * 64;
  int t = threadIdx.x;
  const u16* src = Vh + (size_t)bh * LL * DD;
  {
    int l = t >> 2, dq = (t & 3) * 16;
    short8 v0 = *(const short8*)(src + (size_t)(l0 + l) * DD + dq);
    short8 v1 = *(const short8*)(src + (size_t)(l0 + l) * DD + dq + 8);
    #pragma unroll
    for (int j = 0; j < 8; ++j) T[dq + j][l] = (u16)v0[j];
    #pragma unroll
    for (int j = 0; j < 8; ++j) T[dq + 8 + j][l] = (u16)v1[j];
  }
  __syncthreads();
  {
    int d = t >> 2, lq = (t & 3) * 16;
    u16* dst = Vt + (size_t)bh * DD * LL + (size_t)d * LL + l0 + lq;
    *(short8*)dst = *(const short8*)&T[d][lq];
    *(short8*)(dst + 8) = *(const short8*)&T[d][lq + 8];
  }
}

// ---------------- flash attention (transposed-softmax structure) ----------------
__global__ __launch_bounds__(256, 3) void attn_kernel(
    const u16* __restrict__ Qh, const u16* __restrict__ Kh,
    const u16* __restrict__ Vt, u16* __restrict__ Oh) {
  __shared__ __align__(16) u16 Kl[2][64 * 64];
  __shared__ __align__(16) u16 Vl[2][64 * 64];
  __shared__ __align__(16) unsigned int Pp[4][2][512];

  const int tid = threadIdx.x;
  const int lane = tid & 63, wave = tid >> 6;
  const int lr = lane & 15, lg = lane >> 4;
  const int sw = (lr & 7) * 2;
  const int q0 = blockIdx.x * 128;
  const int bh = blockIdx.y;

  const u16* Qb = Qh + (size_t)bh * LL * DD;
  const u16* Kb = Kh + (size_t)bh * LL * DD;
  const u16* Vb = Vt + (size_t)bh * DD * LL;

  short8 aq[2][2];
  #pragma unroll
  for (int m = 0; m < 2; ++m)
    #pragma unroll
    for (int s = 0; s < 2; ++s)
      aq[m][s] = *(const short8*)(Qb + (size_t)(q0 + wave * 32 + m * 16 + lr) * DD + s * 32 + lg * 8);

  f32x4 z4 = {0.f, 0.f, 0.f, 0.f};
  f32x4 oaccT[2][4];
  #pragma unroll
  for (int m = 0; m < 2; ++m)
    #pragma unroll
    for (int db = 0; db < 4; ++db) oaccT[m][db] = z4;
  float mrow[2] = {-3e38f, -3e38f}, lsum[2] = {0.f, 0.f};

  auto stage = [&](int buf, int kt) {
    int kk0 = kt * 64;
    #pragma unroll
    for (int i = 0; i < 2; ++i) {
      int c = i * 256 + wave * 64 + lane;
      int row = c >> 3, koct = c & 7;
      int ks = koct ^ (row & 7);
      gload_lds16(Kb + (size_t)(kk0 + row) * DD + ks * 8,
                  (char*)&Kl[buf][0] + (size_t)(i * 4 + wave) * 1024);
      gload_lds16(Vb + (size_t)row * LL + kk0 + ks * 8,
                  (char*)&Vl[buf][0] + (size_t)(i * 4 + wave) * 1024);
    }
  };

  stage(0, 0);
  int cur = 0;
  for (int kt = 0; kt < 16; ++kt) {
    if (kt + 1 < 16) {
      stage(cur ^ 1, kt + 1);
      asm volatile("s_waitcnt vmcnt(4)" ::: "memory");
    } else {
      asm volatile("s_waitcnt vmcnt(0)" ::: "memory");
    }
    __builtin_amdgcn_s_barrier();
    __builtin_amdgcn_sched_barrier(0);

    f32x4 ps[2][4];
    #pragma unroll
    for (int m = 0; m < 2; ++m)
      #pragma unroll
      for (int kb = 0; kb < 4; ++kb) ps[m][kb] = z4;
    __builtin_amdgcn_s_setprio(1);
    #pragma unroll
    for (int s = 0; s < 2; ++s) {
      #pragma unroll
      for (int kb = 0; kb < 4; ++kb) {
        int key = kb * 16 + lr;
        int dct = s * 4 + lg;
        short8 ka = *(const short8*)((const char*)&Kl[cur][0] + (size_t)key * 128 + ((dct ^ (key & 7)) << 4));
        ps[0][kb] = __builtin_amdgcn_mfma_f32_16x16x32_bf16(ka, aq[0][s], ps[0][kb], 0, 0, 0);
        ps[1][kb] = __builtin_amdgcn_mfma_f32_16x16x32_bf16(ka, aq[1][s], ps[1][kb], 0, 0, 0);
      }
    }
    __builtin_amdgcn_s_setprio(0);

    #pragma unroll
    for (int m = 0; m < 2; ++m) {
      float a0 = fmaxf(fmaxf(ps[m][0][0], ps[m][0][1]), fmaxf(ps[m][0][2], ps[m][0][3]));
      float a1 = fmaxf(fmaxf(ps[m][1][0], ps[m][1][1]), fmaxf(ps[m][1][2], ps[m][1][3]));
      float a2 = fmaxf(fmaxf(ps[m][2][0], ps[m][2][1]), fmaxf(ps[m][2][2], ps[m][2][3]));
      float a3 = fmaxf(fmaxf(ps[m][3][0], ps[m][3][1]), fmaxf(ps[m][3][2], ps[m][3][3]));
      float v = fmaxf(fmaxf(a0, a1), fmaxf(a2, a3));
      v = fmaxf(v, __shfl_xor(v, 16));
      v = fmaxf(v, __shfl_xor(v, 32));
      float mn = fmaxf(mrow[m], v);
      float alpha = exp2f(mrow[m] - mn);
      mrow[m] = mn;
      float rs = 0.f;
      #pragma unroll
      for (int kb = 0; kb < 4; ++kb)
        #pragma unroll
        for (int r = 0; r < 4; ++r) {
          float p = exp2f(ps[m][kb][r] - mn);
          ps[m][kb][r] = p;
          rs += p;
        }
      rs += __shfl_xor(rs, 16);
      rs += __shfl_xor(rs, 32);
      lsum[m] = lsum[m] * alpha + rs;
      #pragma unroll
      for (int db = 0; db < 4; ++db)
        #pragma unroll
        for (int r = 0; r < 4; ++r) oaccT[m][db][r] *= alpha;
      #pragma unroll
      for (int kb = 0; kb < 4; ++kb) {
        unsigned b0 = __builtin_bit_cast(unsigned, ps[m][kb][0]);
        unsigned b1 = __builtin_bit_cast(unsigned, ps[m][kb][1]);
        unsigned b2 = __builtin_bit_cast(unsigned, ps[m][kb][2]);
        unsigned b3 = __builtin_bit_cast(unsigned, ps[m][kb][3]);
        unsigned lo = ((b0 + 0x8000u) >> 16) | ((b1 + 0x8000u) & 0xFFFF0000u);
        unsigned hi = ((b2 + 0x8000u) >> 16) | ((b3 + 0x8000u) & 0xFFFF0000u);
        int ent = ((kb * 4 + lg) ^ sw) * 2;
        uint2 w; w.x = lo; w.y = hi;
        *(uint2*)&Pp[wave][m][lr * 32 + ent] = w;
      }
    }

    __builtin_amdgcn_s_setprio(1);
    #pragma unroll
    for (int s = 0; s < 2; ++s) {
      short8 ap[2];
      #pragma unroll
      for (int m = 0; m < 2; ++m) {
        int val0 = s * 8 + (lg >> 1) * 4 + (lg & 1) * 2;
        uint4 pw = *(const uint4*)&Pp[wave][m][lr * 32 + ((val0 ^ sw) * 2)];
        ap[m] = __builtin_bit_cast(short8, pw);
      }
      #pragma unroll
      for (int db = 0; db < 4; ++db) {
        int d = db * 16 + lr;
        int kct = s * 4 + lg;
        short8 bv = *(const short8*)((const char*)&Vl[cur][0] + (size_t)d * 128 + ((kct ^ (d & 7)) << 4));
        oaccT[0][db] = __builtin_amdgcn_mfma_f32_16x16x32_bf16(bv, ap[0], oaccT[0][db], 0, 0, 0);
        oaccT[1][db] = __builtin_amdgcn_mfma_f32_16x16x32_bf16(bv, ap[1], oaccT[1][db], 0, 0, 0);
      }
    }
    __builtin_amdgcn_s_setprio(0);

    __builtin_amdgcn_s_barrier();
    cur ^= 1;
  }

  int b = bh >> 3, h = bh & 7;
  #pragma unroll
  for (int m = 0; m < 2; ++m) {
    float inv = 1.0f / lsum[m];
    int q = q0 + wave * 32 + m * 16 + lr;
    #pragma unroll
    for (int db = 0; db < 4; ++db) {
      int d0 = db * 16 + lg * 4;
      short4v o;
      #pragma unroll
      for (int r = 0; r < 4; ++r) o[r] = f2bf(oaccT[m][db][r] * inv);
      *(short4v*)&Oh[(size_t)(b * LL + q) * CC + h * 64 + d0] = o;
    }
  }
}

// ---------------- output projection + residual ----------------
__global__ __launch_bounds__(256) void out_gemm_kernel(
    const u16* __restrict__ Oh, const u16* __restrict__ Wo_bf,
    const float* __restrict__ bo, const float* __restrict__ query,
    float* __restrict__ out) {
  __shared__ __align__(16) u16 Alds[2 * BM * BK];
  __shared__ __align__(16) u16 Blds[2 * BN * BK];
  int m0 = blockIdx.x * BM, n0 = blockIdx.y * BN;
  f32x4 acc[4][4];
  f32x4 z4 = {0.f, 0.f, 0.f, 0.f};
  #pragma unroll
  for (int m = 0; m < 4; ++m)
    #pragma unroll
    for (int n = 0; n < 4; ++n) acc[m][n] = z4;

  gemm_mainloop<CC>(Oh, Wo_bf, m0, n0, Alds, Blds, acc);

  const int lane = threadIdx.x & 63, wave = threadIdx.x >> 6;
  const int wr = wave >> 1, wc = wave & 1;
  const int lr = lane & 15, lg = lane >> 4;
  #pragma unroll
  for (int m = 0; m < 4; ++m) {
    int rowb = m0 + wr * 64 + m * 16 + lg * 4;
    #pragma unroll
    for (int n = 0; n < 4; ++n) {
      int col = n0 + wc * 64 + n * 16 + lr;
      float bias = bo[col];
      #pragma unroll
      for (int r = 0; r < 4; ++r) {
        int rw = rowb + r;
        size_t idx = (size_t)rw * CC + col;
        out[idx] = acc[m][n][r] + bias + query[idx];
      }
    }
  }
}

// ---------------- launcher ----------------
extern "C" void kernel_launch(void* const* d_in, const int* in_sizes, int n_in,
                              void* d_out, int out_size, void* d_ws, size_t ws_size,
                              hipStream_t stream) {
  (void)in_sizes; (void)n_in; (void)out_size;
  const float* query = (const float*)d_in[0];
  const float* qpos  = (const float*)d_in[1];
  const float* Wqc = (const float*)d_in[2];
  const float* bqc = (const float*)d_in[3];
  const float* Wqp = (const float*)d_in[4];
  const float* bqp = (const float*)d_in[5];
  const float* Wkc = (const float*)d_in[6];
  const float* bkc = (const float*)d_in[7];
  const float* Wkp = (const float*)d_in[8];
  const float* bkp = (const float*)d_in[9];
  const float* Wv  = (const float*)d_in[10];
  const float* bv  = (const float*)d_in[11];
  const float* Wo  = (const float*)d_in[12];
  const float* bo  = (const float*)d_in[13];

  char* ws = (char*)d_ws;
  if (ws_size < WS_END) return;

  u16*   Xcat     = (u16*)(ws + WS_XCAT);
  u16*   Wcat     = (u16*)(ws + WS_WCAT);
  u16*   Wo_bf    = (u16*)(ws + WS_WO);
  float* bias_cat = (float*)(ws + WS_BIAS);
  u16*   Qh       = (u16*)(ws + WS_QH);
  u16*   Kh       = (u16*)(ws + WS_KH);
  u16*   Vh       = (u16*)(ws + WS_VH);
  u16*   Oh       = (u16*)(ws + WS_OH);
  u16*   Vtr      = (u16*)(ws + WS_VT);   // aliases Xcat (dead after proj)
  float* out      = (float*)d_out;

  pack_x_kernel<<<dim3(8192), dim3(256), 0, stream>>>(query, qpos, Xcat);
  pack_w_kernel<<<dim3(896), dim3(256), 0, stream>>>(Wqc, Wqp, Wkc, Wkp, Wv, Wo,
                                                     bqc, bqp, bkc, bkp, bv,
                                                     Wcat, Wo_bf, bias_cat);
  proj_gemm_kernel<<<dim3((MROWS / 256) * (NPROJ / 256)), dim3(512), 0, stream>>>(
      Xcat, Wcat, bias_cat, Qh, Kh, Vh);
  vtrans_kernel<<<dim3(LL / 64, BB * HH), dim3(256), 0, stream>>>(Vh, Vtr);
  attn_kernel<<<dim3(LL / 128, BB * HH), dim3(256), 0, stream>>>(Qh, Kh, Vtr, Oh);
  out_gemm_kernel<<<dim3(MROWS / BM, CC / BN), dim3(256), 0, stream>>>(
      Oh, Wo_bf, bo, query, out);
}

// Round 5
// 197.539 us; speedup vs baseline: 1.2223x; 1.0438x over previous
//
#include <hip/hip_runtime.h>

typedef __attribute__((ext_vector_type(8))) short short8;
typedef __attribute__((ext_vector_type(4))) short short4v;
typedef __attribute__((ext_vector_type(4))) float f32x4;
typedef unsigned short u16;

#define QSCALE 0.18033688011112042f   /* 0.125 * log2(e): softmax done in exp2 domain */

#define BB 16
#define LL 1024
#define CC 512
#define HH 8
#define DD 64
#define MROWS (BB*LL)      /* 16384 */
#define KPROJ 1024
#define NPROJ 1536

#define BM 128
#define BN 128
#define BK 32

// workspace offsets (bytes). Vt aliases Xcat (Xcat dead after proj_gemm).
#define WS_XCAT   0ull
#define WS_WCAT   (WS_XCAT + (size_t)MROWS*KPROJ*2)
#define WS_WO     (WS_WCAT + (size_t)NPROJ*KPROJ*2)
#define WS_BIAS   (WS_WO   + (size_t)CC*CC*2)
#define WS_QH     (WS_BIAS + 8192)
#define WS_KH     (WS_QH + (size_t)MROWS*CC*2)
#define WS_VH     (WS_KH + (size_t)MROWS*CC*2)
#define WS_OH     (WS_VH + (size_t)MROWS*CC*2)
#define WS_END    (WS_OH + (size_t)MROWS*CC*2)
#define WS_VT     WS_XCAT

__device__ inline short f2bf(float f) {
  unsigned u = __builtin_bit_cast(unsigned, f);
  u = (u + 0x7FFFu + ((u >> 16) & 1u)) >> 16;
  return (short)u;
}

__device__ inline short8 pack8(const float* src) {
  float4 a = ((const float4*)src)[0];
  float4 b = ((const float4*)src)[1];
  short8 v;
  v[0]=f2bf(a.x); v[1]=f2bf(a.y); v[2]=f2bf(a.z); v[3]=f2bf(a.w);
  v[4]=f2bf(b.x); v[5]=f2bf(b.y); v[6]=f2bf(b.z); v[7]=f2bf(b.w);
  return v;
}

__device__ inline void gload_lds16(const u16* g, char* lds_byte) {
  __builtin_amdgcn_global_load_lds(
      (const __attribute__((address_space(1))) unsigned int*)g,
      (__attribute__((address_space(3))) unsigned int*)lds_byte,
      16, 0, 0);
}

// ---------------- pack kernels ----------------

__global__ __launch_bounds__(256) void pack_x_kernel(
    const float* __restrict__ q, const float* __restrict__ qp, u16* __restrict__ xcat) {
  int o = blockIdx.x * 256 + threadIdx.x;
  int row = o >> 7;
  int kk  = (o & 127) << 3;
  const float* src = (kk < 512) ? (q + (size_t)row * 512 + kk)
                                : (qp + (size_t)row * 512 + (kk - 512));
  short8 v = pack8(src);
  *(short8*)(xcat + (size_t)row * KPROJ + kk) = v;
}

__global__ __launch_bounds__(256) void pack_w_kernel(
    const float* __restrict__ Wqc, const float* __restrict__ Wqp,
    const float* __restrict__ Wkc, const float* __restrict__ Wkp,
    const float* __restrict__ Wv,  const float* __restrict__ Wo,
    const float* __restrict__ bqc, const float* __restrict__ bqp,
    const float* __restrict__ bkc, const float* __restrict__ bkp,
    const float* __restrict__ bv,
    u16* __restrict__ wcat, u16* __restrict__ wo_bf, float* __restrict__ bias_cat) {
  int o = blockIdx.x * 256 + threadIdx.x;
  if (o < 196608) {
    int j = o >> 7;
    int kk = (o & 127) << 3;
    const float* src = nullptr;
    if (j < 512)        src = (kk < 512) ? Wqc + (size_t)j * 512 + kk : Wqp + (size_t)j * 512 + (kk - 512);
    else if (j < 1024) { int jj = j - 512;  src = (kk < 512) ? Wkc + (size_t)jj * 512 + kk : Wkp + (size_t)jj * 512 + (kk - 512); }
    else               { int jj = j - 1024; src = (kk < 512) ? Wv  + (size_t)jj * 512 + kk : nullptr; }
    short8 v = {0,0,0,0,0,0,0,0};
    if (src) v = pack8(src);
    *(short8*)(wcat + (size_t)j * KPROJ + kk) = v;
  } else if (o < 229376) {
    int o2 = o - 196608;
    int j = o2 >> 6;
    int kk = (o2 & 63) << 3;
    short8 v = pack8(Wo + (size_t)j * 512 + kk);
    *(short8*)(wo_bf + (size_t)j * 512 + kk) = v;
  }
  if (o < 1536) {
    float v;
    if (o < 512)       v = bqc[o] + bqp[o];
    else if (o < 1024) v = bkc[o - 512] + bkp[o - 512];
    else               v = bv[o - 1024];
    bias_cat[o] = v;
  }
}

// ---------------- legacy 128x128 GEMM core (out_gemm) ----------------
template <int KDIM>
__device__ inline void gemm_mainloop(const u16* __restrict__ A, const u16* __restrict__ Bw,
                                     int m0, int n0,
                                     u16* Alds, u16* Blds,
                                     f32x4 (&acc)[4][4]) {
  const int tid = threadIdx.x;
  const int lane = tid & 63, wave = tid >> 6;
  const int wr = wave >> 1, wc = wave & 1;
  const int lr = lane & 15, lg = lane >> 4;

  auto stage = [&](int buf, int t) {
    int k0 = t * BK;
    #pragma unroll
    for (int i = 0; i < 2; ++i) {
      int c = (i * 4 + wave) * 64 + lane;
      int row = c >> 2, koct = c & 3;
      char* ldsbaseA = (char*)Alds + (size_t)buf * (BM * BK * 2) + (size_t)(i * 4 + wave) * 1024;
      char* ldsbaseB = (char*)Blds + (size_t)buf * (BN * BK * 2) + (size_t)(i * 4 + wave) * 1024;
      gload_lds16(A  + (size_t)(m0 + row) * KDIM + k0 + koct * 8, ldsbaseA);
      gload_lds16(Bw + (size_t)(n0 + row) * KDIM + k0 + koct * 8, ldsbaseB);
    }
  };

  stage(0, 0);
  constexpr int NT = KDIM / BK;
  int cur = 0;
  for (int t = 0; t < NT; ++t) {
    __syncthreads();
    if (t + 1 < NT) stage(cur ^ 1, t + 1);
    const u16* Ab = Alds + (size_t)cur * (BM * BK);
    const u16* Bb = Blds + (size_t)cur * (BN * BK);
    short8 af[4], bfr[4];
    #pragma unroll
    for (int m = 0; m < 4; ++m)
      af[m] = *(const short8*)(Ab + (size_t)(wr * 64 + m * 16 + lr) * BK + lg * 8);
    #pragma unroll
    for (int n = 0; n < 4; ++n)
      bfr[n] = *(const short8*)(Bb + (size_t)(wc * 64 + n * 16 + lr) * BK + lg * 8);
    #pragma unroll
    for (int m = 0; m < 4; ++m)
      #pragma unroll
      for (int n = 0; n < 4; ++n)
        acc[m][n] = __builtin_amdgcn_mfma_f32_16x16x32_bf16(af[m], bfr[n], acc[m][n], 0, 0, 0);
    cur ^= 1;
  }
}

// ---------------- projection GEMM: 256x256 tile, BK=64, 8 waves, 8-phase ----------------
__global__ __launch_bounds__(512, 2) void proj_gemm_kernel(
    const u16* __restrict__ Xcat, const u16* __restrict__ Wcat,
    const float* __restrict__ bias_cat,
    u16* __restrict__ Qh, u16* __restrict__ Kh, u16* __restrict__ Vh) {
  __shared__ __align__(16) u16 lds[2 * 32768];   // 128 KB

  // bijective XCD swizzle (384 blocks, 384 % 8 == 0)
  int id0 = blockIdx.x;
  int swz = (id0 & 7) * 48 + (id0 >> 3);
  int bx = swz / 6, by = swz % 6;
  const int m0 = bx * 256, n0 = by * 256;

  const int tid = threadIdx.x;
  const int lane = tid & 63, wave = tid >> 6;
  const int wr = wave >> 2, wc = wave & 3;
  const int lr = lane & 15, lg = lane >> 4;

  auto stage_unit = [&](int buf, int u, int k0) {
    const u16* base = (u < 2) ? (Xcat + (size_t)(m0 + u * 128) * KPROJ + k0)
                              : (Wcat + (size_t)(n0 + (u - 2) * 128) * KPROJ + k0);
    #pragma unroll
    for (int i = 0; i < 2; ++i) {
      int s = i * 512 + tid;
      int row = s >> 3, col = s & 7;
      int colp = col ^ (row & 7);
      gload_lds16(base + (size_t)row * KPROJ + colp * 8,
                  (char*)lds + ((size_t)buf * 32768 + (size_t)u * 8192) * 2
                             + (size_t)(i * 512 + wave * 64) * 16);
    }
  };

  auto rdW = [&](int buf, int nf, int ks) {
    int rowl = (wc & 1) * 64 + nf * 16 + lr;
    int chunk = (ks * 4 + lg) ^ (rowl & 7);
    return *(const short8*)(lds + (size_t)buf * 32768 + (size_t)(2 + (wc >> 1)) * 8192
                            + (size_t)rowl * 64 + chunk * 8);
  };
  auto rdX = [&](int buf, int mf, int ks) {
    int rowl = mf * 16 + lr;
    int chunk = (ks * 4 + lg) ^ (rowl & 7);
    return *(const short8*)(lds + (size_t)buf * 32768 + (size_t)wr * 8192
                            + (size_t)rowl * 64 + chunk * 8);
  };

  f32x4 acc[8][4];
  f32x4 z4 = {0.f, 0.f, 0.f, 0.f};
  #pragma unroll
  for (int mf = 0; mf < 8; ++mf)
    #pragma unroll
    for (int nf = 0; nf < 4; ++nf) acc[mf][nf] = z4;

  #pragma unroll
  for (int u = 0; u < 4; ++u) stage_unit(0, u, 0);
  asm volatile("s_waitcnt vmcnt(0)" ::: "memory");
  __builtin_amdgcn_s_barrier();
  __builtin_amdgcn_sched_barrier(0);

  short8 wfr[4][2];
  constexpr int NT = KPROJ / 64;
  for (int kt = 0; kt < NT; ++kt) {
    const int b = kt & 1;
    const bool pf = (kt + 1 < NT);
    #pragma unroll
    for (int p = 0; p < 4; ++p) {
      if (p == 0) {
        #pragma unroll
        for (int nf = 0; nf < 4; ++nf)
          #pragma unroll
          for (int ks = 0; ks < 2; ++ks) wfr[nf][ks] = rdW(b, nf, ks);
      }
      short8 xf[2][2];
      #pragma unroll
      for (int mm = 0; mm < 2; ++mm)
        #pragma unroll
        for (int ks = 0; ks < 2; ++ks) xf[mm][ks] = rdX(b, p * 2 + mm, ks);
      if (pf) stage_unit(b ^ 1, p, (kt + 1) * 64);
      __builtin_amdgcn_s_barrier();
      __builtin_amdgcn_sched_barrier(0);
      __builtin_amdgcn_s_setprio(1);
      #pragma unroll
      for (int mm = 0; mm < 2; ++mm)
        #pragma unroll
        for (int nf = 0; nf < 4; ++nf)
          #pragma unroll
          for (int ks = 0; ks < 2; ++ks)
            acc[p * 2 + mm][nf] = __builtin_amdgcn_mfma_f32_16x16x32_bf16(
                wfr[nf][ks], xf[mm][ks], acc[p * 2 + mm][nf], 0, 0, 0);
      __builtin_amdgcn_s_setprio(0);
      if (p == 3 && pf) asm volatile("s_waitcnt vmcnt(0)" ::: "memory");
      __builtin_amdgcn_s_barrier();
      __builtin_amdgcn_sched_barrier(0);
    }
  }

  const int cbase = n0 + wc * 64 + lg * 4;
  #pragma unroll
  for (int mf = 0; mf < 8; ++mf) {
    int lglob = m0 + wr * 128 + mf * 16 + lr;
    int bidx = lglob >> 10, lrow = lglob & 1023;
    #pragma unroll
    for (int nf = 0; nf < 4; ++nf) {
      int c = cbase + nf * 16;
      float4 bb = *(const float4*)&bias_cat[c];
      int sec = c >> 9, cj = c & 511;
      int h = cj >> 6, d0 = cj & 63;
      size_t idx = ((size_t)(bidx * HH + h) * LL + lrow) * DD + d0;
      float v0 = acc[mf][nf][0] + bb.x;
      float v1 = acc[mf][nf][1] + bb.y;
      float v2 = acc[mf][nf][2] + bb.z;
      float v3 = acc[mf][nf][3] + bb.w;
      if (sec == 0) { v0 *= QSCALE; v1 *= QSCALE; v2 *= QSCALE; v3 *= QSCALE; }
      short4v o;
      o[0] = f2bf(v0); o[1] = f2bf(v1); o[2] = f2bf(v2); o[3] = f2bf(v3);
      u16* dst = (sec == 0) ? Qh : (sec == 1) ? Kh : Vh;
      *(short4v*)&dst[idx] = o;
    }
  }
}

// ---------------- V transpose: Vh[bh][l][d] -> Vt[bh][d][l] ----------------
__global__ __launch_bounds__(256) void vtrans_kernel(
    const u16* __restrict__ Vh, u16* __restrict__ Vt) {
  __shared__ u16 T[64][72];
  int bh = blockIdx.y;
  int l0 = blockIdx.x * 64;
  int t = threadIdx.x;
  const u16* src = Vh + (size_t)bh * LL * DD;
  {
    int l = t >> 2, dq = (t & 3) * 16;
    short8 v0 = *(const short8*)(src + (size_t)(l0 + l) * DD + dq);
    short8 v1 = *(const short8*)(src + (size_t)(l0 + l) * DD + dq + 8);
    #pragma unroll
    for (int j = 0; j < 8; ++j) T[dq + j][l] = (u16)v0[j];
    #pragma unroll
    for (int j = 0; j < 8; ++j) T[dq + 8 + j][l] = (u16)v1[j];
  }
  __syncthreads();
  {
    int d = t >> 2, lq = (t & 3) * 16;
    u16* dst = Vt + (size_t)bh * DD * LL + (size_t)d * LL + l0 + lq;
    *(short8*)dst = *(const short8*)&T[d][lq];
    *(short8*)(dst + 8) = *(const short8*)&T[d][lq + 8];
  }
}

// ---------------- flash attention (transposed-softmax, 4 blocks/CU) ----------------
// 1D grid 1024. XCD-locality map: all 8 q-blocks of a bh share n&7 -> same XCD L2.
// S^T = mfma(K,Q): lane-local softmax. Sequential-m P transpose through shared
// per-wave 2KB LDS buffer (wave-private, same-wave DS ordering). Defer-max (T13),
// cvt_pk bf16 packing (T12). LDS 40KB -> 4 blocks/CU.
__global__ __launch_bounds__(256, 4) void attn_kernel(
    const u16* __restrict__ Qh, const u16* __restrict__ Kh,
    const u16* __restrict__ Vt, u16* __restrict__ Oh) {
  __shared__ __align__(16) u16 Kl[2][64 * 64];
  __shared__ __align__(16) u16 Vl[2][64 * 64];
  __shared__ __align__(16) unsigned int Pp[4][512];   // per-wave 2KB

  const int tid = threadIdx.x;
  const int lane = tid & 63, wave = tid >> 6;
  const int lr = lane & 15, lg = lane >> 4;
  const int sw = (lr & 7) * 2;
  int n = blockIdx.x;
  int kk = n >> 3;
  const int bh = (n & 7) * 16 + (kk >> 3);
  const int q0 = (kk & 7) * 128;

  const u16* Qb = Qh + (size_t)bh * LL * DD;
  const u16* Kb = Kh + (size_t)bh * LL * DD;
  const u16* Vb = Vt + (size_t)bh * DD * LL;

  short8 aq[2][2];
  #pragma unroll
  for (int m = 0; m < 2; ++m)
    #pragma unroll
    for (int s = 0; s < 2; ++s)
      aq[m][s] = *(const short8*)(Qb + (size_t)(q0 + wave * 32 + m * 16 + lr) * DD + s * 32 + lg * 8);

  f32x4 z4 = {0.f, 0.f, 0.f, 0.f};
  f32x4 oaccT[2][4];
  #pragma unroll
  for (int m = 0; m < 2; ++m)
    #pragma unroll
    for (int db = 0; db < 4; ++db) oaccT[m][db] = z4;
  float mrow[2] = {-3e38f, -3e38f}, lsum[2] = {0.f, 0.f};

  auto stage = [&](int buf, int kt) {
    int kk0 = kt * 64;
    #pragma unroll
    for (int i = 0; i < 2; ++i) {
      int c = i * 256 + wave * 64 + lane;
      int row = c >> 3, koct = c & 7;
      int ks = koct ^ (row & 7);
      gload_lds16(Kb + (size_t)(kk0 + row) * DD + ks * 8,
                  (char*)&Kl[buf][0] + (size_t)(i * 4 + wave) * 1024);
      gload_lds16(Vb + (size_t)row * LL + kk0 + ks * 8,
                  (char*)&Vl[buf][0] + (size_t)(i * 4 + wave) * 1024);
    }
  };

  stage(0, 0);
  int cur = 0;
  for (int kt = 0; kt < 16; ++kt) {
    if (kt + 1 < 16) {
      stage(cur ^ 1, kt + 1);
      asm volatile("s_waitcnt vmcnt(4)" ::: "memory");
    } else {
      asm volatile("s_waitcnt vmcnt(0)" ::: "memory");
    }
    __builtin_amdgcn_s_barrier();
    __builtin_amdgcn_sched_barrier(0);

    // ---- S^T = K @ Q^T ----
    f32x4 ps[2][4];
    #pragma unroll
    for (int m = 0; m < 2; ++m)
      #pragma unroll
      for (int kb = 0; kb < 4; ++kb) ps[m][kb] = z4;
    __builtin_amdgcn_s_setprio(1);
    #pragma unroll
    for (int s = 0; s < 2; ++s) {
      #pragma unroll
      for (int kb = 0; kb < 4; ++kb) {
        int key = kb * 16 + lr;
        int dct = s * 4 + lg;
        short8 ka = *(const short8*)((const char*)&Kl[cur][0] + (size_t)key * 128 + ((dct ^ (key & 7)) << 4));
        ps[0][kb] = __builtin_amdgcn_mfma_f32_16x16x32_bf16(ka, aq[0][s], ps[0][kb], 0, 0, 0);
        ps[1][kb] = __builtin_amdgcn_mfma_f32_16x16x32_bf16(ka, aq[1][s], ps[1][kb], 0, 0, 0);
      }
    }
    __builtin_amdgcn_s_setprio(0);

    // ---- lane-local online softmax with defer-max ----
    #pragma unroll
    for (int m = 0; m < 2; ++m) {
      float a0 = fmaxf(fmaxf(ps[m][0][0], ps[m][0][1]), fmaxf(ps[m][0][2], ps[m][0][3]));
      float a1 = fmaxf(fmaxf(ps[m][1][0], ps[m][1][1]), fmaxf(ps[m][1][2], ps[m][1][3]));
      float a2 = fmaxf(fmaxf(ps[m][2][0], ps[m][2][1]), fmaxf(ps[m][2][2], ps[m][2][3]));
      float a3 = fmaxf(fmaxf(ps[m][3][0], ps[m][3][1]), fmaxf(ps[m][3][2], ps[m][3][3]));
      float pmax = fmaxf(fmaxf(a0, a1), fmaxf(a2, a3));
      pmax = fmaxf(pmax, __shfl_xor(pmax, 16));
      pmax = fmaxf(pmax, __shfl_xor(pmax, 32));
      if (!__all(pmax <= mrow[m] + 8.f)) {
        float mn = fmaxf(mrow[m], pmax);
        float alpha = exp2f(mrow[m] - mn);
        mrow[m] = mn;
        lsum[m] *= alpha;
        #pragma unroll
        for (int db = 0; db < 4; ++db)
          #pragma unroll
          for (int r = 0; r < 4; ++r) oaccT[m][db][r] *= alpha;
      }
      float rs = 0.f;
      #pragma unroll
      for (int kb = 0; kb < 4; ++kb)
        #pragma unroll
        for (int r = 0; r < 4; ++r) {
          float p = exp2f(ps[m][kb][r] - mrow[m]);
          ps[m][kb][r] = p;
          rs += p;
        }
      rs += __shfl_xor(rs, 16);
      rs += __shfl_xor(rs, 32);
      lsum[m] += rs;
    }

    // ---- O^T += V^T @ P, sequential m through shared per-wave P buffer ----
    __builtin_amdgcn_s_setprio(1);
    #pragma unroll
    for (int m = 0; m < 2; ++m) {
      #pragma unroll
      for (int kb = 0; kb < 4; ++kb) {
        unsigned lo, hi;
        asm("v_cvt_pk_bf16_f32 %0, %1, %2" : "=v"(lo) : "v"(ps[m][kb][0]), "v"(ps[m][kb][1]));
        asm("v_cvt_pk_bf16_f32 %0, %1, %2" : "=v"(hi) : "v"(ps[m][kb][2]), "v"(ps[m][kb][3]));
        uint2 w; w.x = lo; w.y = hi;
        *(uint2*)&Pp[wave][lr * 32 + (((kb * 4 + lg) ^ sw) * 2)] = w;
      }
      asm volatile("s_waitcnt lgkmcnt(0)" ::: "memory");
      __builtin_amdgcn_sched_barrier(0);
      #pragma unroll
      for (int s = 0; s < 2; ++s) {
        int val0 = s * 8 + lg * 2;
        uint4 pw = *(const uint4*)&Pp[wave][lr * 32 + ((val0 ^ sw) * 2)];
        short8 ap = __builtin_bit_cast(short8, pw);
        #pragma unroll
        for (int db = 0; db < 4; ++db) {
          int d = db * 16 + lr;
          int kct = s * 4 + lg;
          short8 bv = *(const short8*)((const char*)&Vl[cur][0] + (size_t)d * 128 + ((kct ^ (d & 7)) << 4));
          oaccT[m][db] = __builtin_amdgcn_mfma_f32_16x16x32_bf16(bv, ap, oaccT[m][db], 0, 0, 0);
        }
      }
    }
    __builtin_amdgcn_s_setprio(0);

    __builtin_amdgcn_s_barrier();
    cur ^= 1;
  }

  int b = bh >> 3, h = bh & 7;
  #pragma unroll
  for (int m = 0; m < 2; ++m) {
    float inv = 1.0f / lsum[m];
    int q = q0 + wave * 32 + m * 16 + lr;
    #pragma unroll
    for (int db = 0; db < 4; ++db) {
      int d0 = db * 16 + lg * 4;
      short4v o;
      #pragma unroll
      for (int r = 0; r < 4; ++r) o[r] = f2bf(oaccT[m][db][r] * inv);
      *(short4v*)&Oh[(size_t)(b * LL + q) * CC + h * 64 + d0] = o;
    }
  }
}

// ---------------- output projection + residual ----------------
__global__ __launch_bounds__(256) void out_gemm_kernel(
    const u16* __restrict__ Oh, const u16* __restrict__ Wo_bf,
    const float* __restrict__ bo, const float* __restrict__ query,
    float* __restrict__ out) {
  __shared__ __align__(16) u16 Alds[2 * BM * BK];
  __shared__ __align__(16) u16 Blds[2 * BN * BK];
  int m0 = blockIdx.x * BM, n0 = blockIdx.y * BN;
  f32x4 acc[4][4];
  f32x4 z4 = {0.f, 0.f, 0.f, 0.f};
  #pragma unroll
  for (int m = 0; m < 4; ++m)
    #pragma unroll
    for (int n = 0; n < 4; ++n) acc[m][n] = z4;

  gemm_mainloop<CC>(Oh, Wo_bf, m0, n0, Alds, Blds, acc);

  const int lane = threadIdx.x & 63, wave = threadIdx.x >> 6;
  const int wr = wave >> 1, wc = wave & 1;
  const int lr = lane & 15, lg = lane >> 4;
  #pragma unroll
  for (int m = 0; m < 4; ++m) {
    int rowb = m0 + wr * 64 + m * 16 + lg * 4;
    #pragma unroll
    for (int n = 0; n < 4; ++n) {
      int col = n0 + wc * 64 + n * 16 + lr;
      float bias = bo[col];
      #pragma unroll
      for (int r = 0; r < 4; ++r) {
        int rw = rowb + r;
        size_t idx = (size_t)rw * CC + col;
        out[idx] = acc[m][n][r] + bias + query[idx];
      }
    }
  }
}

// ---------------- launcher ----------------
extern "C" void kernel_launch(void* const* d_in, const int* in_sizes, int n_in,
                              void* d_out, int out_size, void* d_ws, size_t ws_size,
                              hipStream_t stream) {
  (void)in_sizes; (void)n_in; (void)out_size;
  const float* query = (const float*)d_in[0];
  const float* qpos  = (const float*)d_in[1];
  const float* Wqc = (const float*)d_in[2];
  const float* bqc = (const float*)d_in[3];
  const float* Wqp = (const float*)d_in[4];
  const float* bqp = (const float*)d_in[5];
  const float* Wkc = (const float*)d_in[6];
  const float* bkc = (const float*)d_in[7];
  const float* Wkp = (const float*)d_in[8];
  const float* bkp = (const float*)d_in[9];
  const float* Wv  = (const float*)d_in[10];
  const float* bv  = (const float*)d_in[11];
  const float* Wo  = (const float*)d_in[12];
  const float* bo  = (const float*)d_in[13];

  char* ws = (char*)d_ws;
  if (ws_size < WS_END) return;

  u16*   Xcat     = (u16*)(ws + WS_XCAT);
  u16*   Wcat     = (u16*)(ws + WS_WCAT);
  u16*   Wo_bf    = (u16*)(ws + WS_WO);
  float* bias_cat = (float*)(ws + WS_BIAS);
  u16*   Qh       = (u16*)(ws + WS_QH);
  u16*   Kh       = (u16*)(ws + WS_KH);
  u16*   Vh       = (u16*)(ws + WS_VH);
  u16*   Oh       = (u16*)(ws + WS_OH);
  u16*   Vtr      = (u16*)(ws + WS_VT);   // aliases Xcat (dead after proj)
  float* out      = (float*)d_out;

  pack_x_kernel<<<dim3(8192), dim3(256), 0, stream>>>(query, qpos, Xcat);
  pack_w_kernel<<<dim3(896), dim3(256), 0, stream>>>(Wqc, Wqp, Wkc, Wkp, Wv, Wo,
                                                     bqc, bqp, bkc, bkp, bv,
                                                     Wcat, Wo_bf, bias_cat);
  proj_gemm_kernel<<<dim3((MROWS / 256) * (NPROJ / 256)), dim3(512), 0, stream>>>(
      Xcat, Wcat, bias_cat, Qh, Kh, Vh);
  vtrans_kernel<<<dim3(LL / 64, BB * HH), dim3(256), 0, stream>>>(Vh, Vtr);
  attn_kernel<<<dim3(1024), dim3(256), 0, stream>>>(Qh, Kh, Vtr, Oh);
  out_gemm_kernel<<<dim3(MROWS / BM, CC / BN), dim3(256), 0, stream>>>(
      Oh, Wo_bf, bo, query, out);
}

// Round 6
// 195.774 us; speedup vs baseline: 1.2334x; 1.0090x over previous
//
#include <hip/hip_runtime.h>

typedef __attribute__((ext_vector_type(8))) short short8;
typedef __attribute__((ext_vector_type(4))) short short4v;
typedef __attribute__((ext_vector_type(4))) float f32x4;
typedef unsigned short u16;

#define QSCALE 0.18033688011112042f   /* 0.125 * log2(e): softmax done in exp2 domain */

#define BB 16
#define LL 1024
#define CC 512
#define HH 8
#define DD 64
#define MROWS (BB*LL)      /* 16384 */
#define KPROJ 1024
#define NPROJ 1536

#define BM 128
#define BN 128
#define BK 32

// workspace offsets (bytes). Vt aliases Xcat (Xcat dead after proj_gemm).
#define WS_XCAT   0ull
#define WS_WCAT   (WS_XCAT + (size_t)MROWS*KPROJ*2)
#define WS_WO     (WS_WCAT + (size_t)NPROJ*KPROJ*2)
#define WS_BIAS   (WS_WO   + (size_t)CC*CC*2)
#define WS_QH     (WS_BIAS + 8192)
#define WS_KH     (WS_QH + (size_t)MROWS*CC*2)
#define WS_VH     (WS_KH + (size_t)MROWS*CC*2)
#define WS_OH     (WS_VH + (size_t)MROWS*CC*2)
#define WS_END    (WS_OH + (size_t)MROWS*CC*2)
#define WS_VT     WS_XCAT

__device__ inline short f2bf(float f) {
  unsigned u = __builtin_bit_cast(unsigned, f);
  u = (u + 0x7FFFu + ((u >> 16) & 1u)) >> 16;
  return (short)u;
}

__device__ inline short8 pack8(const float* src) {
  float4 a = ((const float4*)src)[0];
  float4 b = ((const float4*)src)[1];
  short8 v;
  v[0]=f2bf(a.x); v[1]=f2bf(a.y); v[2]=f2bf(a.z); v[3]=f2bf(a.w);
  v[4]=f2bf(b.x); v[5]=f2bf(b.y); v[6]=f2bf(b.z); v[7]=f2bf(b.w);
  return v;
}

__device__ inline void gload_lds16(const u16* g, char* lds_byte) {
  __builtin_amdgcn_global_load_lds(
      (const __attribute__((address_space(1))) unsigned int*)g,
      (__attribute__((address_space(3))) unsigned int*)lds_byte,
      16, 0, 0);
}

// ---------------- pack kernels ----------------

__global__ __launch_bounds__(256) void pack_x_kernel(
    const float* __restrict__ q, const float* __restrict__ qp, u16* __restrict__ xcat) {
  int o = blockIdx.x * 256 + threadIdx.x;
  int row = o >> 7;
  int kk  = (o & 127) << 3;
  const float* src = (kk < 512) ? (q + (size_t)row * 512 + kk)
                                : (qp + (size_t)row * 512 + (kk - 512));
  short8 v = pack8(src);
  *(short8*)(xcat + (size_t)row * KPROJ + kk) = v;
}

__global__ __launch_bounds__(256) void pack_w_kernel(
    const float* __restrict__ Wqc, const float* __restrict__ Wqp,
    const float* __restrict__ Wkc, const float* __restrict__ Wkp,
    const float* __restrict__ Wv,  const float* __restrict__ Wo,
    const float* __restrict__ bqc, const float* __restrict__ bqp,
    const float* __restrict__ bkc, const float* __restrict__ bkp,
    const float* __restrict__ bv,
    u16* __restrict__ wcat, u16* __restrict__ wo_bf, float* __restrict__ bias_cat) {
  int o = blockIdx.x * 256 + threadIdx.x;
  if (o < 196608) {
    int j = o >> 7;
    int kk = (o & 127) << 3;
    const float* src = nullptr;
    if (j < 512)        src = (kk < 512) ? Wqc + (size_t)j * 512 + kk : Wqp + (size_t)j * 512 + (kk - 512);
    else if (j < 1024) { int jj = j - 512;  src = (kk < 512) ? Wkc + (size_t)jj * 512 + kk : Wkp + (size_t)jj * 512 + (kk - 512); }
    else               { int jj = j - 1024; src = (kk < 512) ? Wv  + (size_t)jj * 512 + kk : nullptr; }
    short8 v = {0,0,0,0,0,0,0,0};
    if (src) v = pack8(src);
    *(short8*)(wcat + (size_t)j * KPROJ + kk) = v;
  } else if (o < 229376) {
    int o2 = o - 196608;
    int j = o2 >> 6;
    int kk = (o2 & 63) << 3;
    short8 v = pack8(Wo + (size_t)j * 512 + kk);
    *(short8*)(wo_bf + (size_t)j * 512 + kk) = v;
  }
  if (o < 1536) {
    float v;
    if (o < 512)       v = bqc[o] + bqp[o];
    else if (o < 1024) v = bkc[o - 512] + bkp[o - 512];
    else               v = bv[o - 1024];
    bias_cat[o] = v;
  }
}

// ---------------- legacy 128x128 GEMM core (out_gemm) ----------------
template <int KDIM>
__device__ inline void gemm_mainloop(const u16* __restrict__ A, const u16* __restrict__ Bw,
                                     int m0, int n0,
                                     u16* Alds, u16* Blds,
                                     f32x4 (&acc)[4][4]) {
  const int tid = threadIdx.x;
  const int lane = tid & 63, wave = tid >> 6;
  const int wr = wave >> 1, wc = wave & 1;
  const int lr = lane & 15, lg = lane >> 4;

  auto stage = [&](int buf, int t) {
    int k0 = t * BK;
    #pragma unroll
    for (int i = 0; i < 2; ++i) {
      int c = (i * 4 + wave) * 64 + lane;
      int row = c >> 2, koct = c & 3;
      char* ldsbaseA = (char*)Alds + (size_t)buf * (BM * BK * 2) + (size_t)(i * 4 + wave) * 1024;
      char* ldsbaseB = (char*)Blds + (size_t)buf * (BN * BK * 2) + (size_t)(i * 4 + wave) * 1024;
      gload_lds16(A  + (size_t)(m0 + row) * KDIM + k0 + koct * 8, ldsbaseA);
      gload_lds16(Bw + (size_t)(n0 + row) * KDIM + k0 + koct * 8, ldsbaseB);
    }
  };

  stage(0, 0);
  constexpr int NT = KDIM / BK;
  int cur = 0;
  for (int t = 0; t < NT; ++t) {
    __syncthreads();
    if (t + 1 < NT) stage(cur ^ 1, t + 1);
    const u16* Ab = Alds + (size_t)cur * (BM * BK);
    const u16* Bb = Blds + (size_t)cur * (BN * BK);
    short8 af[4], bfr[4];
    #pragma unroll
    for (int m = 0; m < 4; ++m)
      af[m] = *(const short8*)(Ab + (size_t)(wr * 64 + m * 16 + lr) * BK + lg * 8);
    #pragma unroll
    for (int n = 0; n < 4; ++n)
      bfr[n] = *(const short8*)(Bb + (size_t)(wc * 64 + n * 16 + lr) * BK + lg * 8);
    #pragma unroll
    for (int m = 0; m < 4; ++m)
      #pragma unroll
      for (int n = 0; n < 4; ++n)
        acc[m][n] = __builtin_amdgcn_mfma_f32_16x16x32_bf16(af[m], bfr[n], acc[m][n], 0, 0, 0);
    cur ^= 1;
  }
}

// ---------------- projection GEMM: 256x256 tile, BK=64, 8 waves ----------------
// T4 fix: consumption-ordered staging (B units first, then A low-halves, then
// A high-halves) + counted vmcnt(4)/vmcnt(2) at phase 1/3 ends. Never vmcnt(0)
// in the main loop; loads stay in flight across barriers.
__global__ __launch_bounds__(512, 2) void proj_gemm_kernel(
    const u16* __restrict__ Xcat, const u16* __restrict__ Wcat,
    const float* __restrict__ bias_cat,
    u16* __restrict__ Qh, u16* __restrict__ Kh, u16* __restrict__ Vh) {
  __shared__ __align__(16) u16 lds[2 * 32768];   // 128 KB

  // bijective XCD swizzle (384 blocks, 384 % 8 == 0)
  int id0 = blockIdx.x;
  int swz = (id0 & 7) * 48 + (id0 >> 3);
  int bx = swz / 6, by = swz % 6;
  const int m0 = bx * 256, n0 = by * 256;

  const int tid = threadIdx.x;
  const int lane = tid & 63, wave = tid >> 6;
  const int wr = wave >> 2, wc = wave & 3;
  const int lr = lane & 15, lg = lane >> 4;

  // stage one 8KB half-unit: unit u in {0:A rows 0-127, 1:A rows 128-255,
  // 2:B rows 0-127, 3:B rows 128-255}; half i covers unit-rows i*64..i*64+63.
  auto stage_half = [&](int buf, int u, int i, int k0) {
    const u16* base = (u < 2) ? (Xcat + (size_t)(m0 + u * 128) * KPROJ + k0)
                              : (Wcat + (size_t)(n0 + (u - 2) * 128) * KPROJ + k0);
    int s = i * 512 + tid;
    int row = s >> 3, col = s & 7;
    int colp = col ^ (row & 7);              // inverse swizzle on SOURCE, linear dest
    gload_lds16(base + (size_t)row * KPROJ + colp * 8,
                (char*)lds + ((size_t)buf * 32768 + (size_t)u * 8192) * 2
                           + (size_t)(i * 512 + wave * 64) * 16);
  };

  auto rdW = [&](int buf, int nf, int ks) {
    int rowl = (wc & 1) * 64 + nf * 16 + lr;
    int chunk = (ks * 4 + lg) ^ (rowl & 7);
    return *(const short8*)(lds + (size_t)buf * 32768 + (size_t)(2 + (wc >> 1)) * 8192
                            + (size_t)rowl * 64 + chunk * 8);
  };
  auto rdX = [&](int buf, int mf, int ks) {
    int rowl = mf * 16 + lr;
    int chunk = (ks * 4 + lg) ^ (rowl & 7);
    return *(const short8*)(lds + (size_t)buf * 32768 + (size_t)wr * 8192
                            + (size_t)rowl * 64 + chunk * 8);
  };

  f32x4 acc[8][4];
  f32x4 z4 = {0.f, 0.f, 0.f, 0.f};
  #pragma unroll
  for (int mf = 0; mf < 8; ++mf)
    #pragma unroll
    for (int nf = 0; nf < 4; ++nf) acc[mf][nf] = z4;

  // prologue: stage K-tile 0 into buf 0, drain, barrier
  #pragma unroll
  for (int u = 0; u < 4; ++u) {
    stage_half(0, u, 0, 0);
    stage_half(0, u, 1, 0);
  }
  asm volatile("s_waitcnt vmcnt(0)" ::: "memory");
  __builtin_amdgcn_s_barrier();
  __builtin_amdgcn_sched_barrier(0);

  short8 wfr[4][2];
  constexpr int NT = KPROJ / 64;   // 16 K-tiles
  for (int kt = 0; kt < NT; ++kt) {
    const int b = kt & 1;
    const bool pf = (kt + 1 < NT);
    const int k1 = (kt + 1) * 64;
    #pragma unroll
    for (int p = 0; p < 4; ++p) {
      // ds-reads for this phase (B-frags once per tile, held in regs)
      if (p == 0) {
        #pragma unroll
        for (int nf = 0; nf < 4; ++nf)
          #pragma unroll
          for (int ks = 0; ks < 2; ++ks) wfr[nf][ks] = rdW(b, nf, ks);
      }
      short8 xf[2][2];
      #pragma unroll
      for (int mm = 0; mm < 2; ++mm)
        #pragma unroll
        for (int ks = 0; ks < 2; ++ks) xf[mm][ks] = rdX(b, p * 2 + mm, ks);
      // consumption-ordered prefetch of tile kt+1 into the dead buffer:
      // p0: B-unit2, p1: B-unit3, p2: A0.lo+A1.lo, p3: A0.hi+A1.hi
      if (pf) {
        if (p == 0)      { stage_half(b ^ 1, 2, 0, k1); stage_half(b ^ 1, 2, 1, k1); }
        else if (p == 1) { stage_half(b ^ 1, 3, 0, k1); stage_half(b ^ 1, 3, 1, k1); }
        else if (p == 2) { stage_half(b ^ 1, 0, 0, k1); stage_half(b ^ 1, 1, 0, k1); }
        else             { stage_half(b ^ 1, 0, 1, k1); stage_half(b ^ 1, 1, 1, k1); }
      }
      __builtin_amdgcn_s_barrier();
      __builtin_amdgcn_sched_barrier(0);
      __builtin_amdgcn_s_setprio(1);
      #pragma unroll
      for (int mm = 0; mm < 2; ++mm)
        #pragma unroll
        for (int nf = 0; nf < 4; ++nf)
          #pragma unroll
          for (int ks = 0; ks < 2; ++ks)
            acc[p * 2 + mm][nf] = __builtin_amdgcn_mfma_f32_16x16x32_bf16(
                wfr[nf][ks], xf[mm][ks], acc[p * 2 + mm][nf], 0, 0, 0);
      __builtin_amdgcn_s_setprio(0);
      // counted waits, never 0: end-p1 protects next phase's A.hi reads;
      // end-p3 protects next tile's B + A.lo reads. (Trivially pass on last tile.)
      if (p == 1) asm volatile("s_waitcnt vmcnt(4)" ::: "memory");
      if (p == 3) asm volatile("s_waitcnt vmcnt(2)" ::: "memory");
      __builtin_amdgcn_s_barrier();
      __builtin_amdgcn_sched_barrier(0);
    }
  }

  // epilogue: lane frag (mf,nf) -> out row l = m0+wr*128+mf*16+lr,
  // cols c = n0+wc*64+nf*16+lg*4 .. +3 (consecutive) -> 8B stores
  const int cbase = n0 + wc * 64 + lg * 4;
  #pragma unroll
  for (int mf = 0; mf < 8; ++mf) {
    int lglob = m0 + wr * 128 + mf * 16 + lr;
    int bidx = lglob >> 10, lrow = lglob & 1023;
    #pragma unroll
    for (int nf = 0; nf < 4; ++nf) {
      int c = cbase + nf * 16;
      float4 bb = *(const float4*)&bias_cat[c];
      int sec = c >> 9, cj = c & 511;
      int h = cj >> 6, d0 = cj & 63;
      size_t idx = ((size_t)(bidx * HH + h) * LL + lrow) * DD + d0;
      float v0 = acc[mf][nf][0] + bb.x;
      float v1 = acc[mf][nf][1] + bb.y;
      float v2 = acc[mf][nf][2] + bb.z;
      float v3 = acc[mf][nf][3] + bb.w;
      if (sec == 0) { v0 *= QSCALE; v1 *= QSCALE; v2 *= QSCALE; v3 *= QSCALE; }
      short4v o;
      o[0] = f2bf(v0); o[1] = f2bf(v1); o[2] = f2bf(v2); o[3] = f2bf(v3);
      u16* dst = (sec == 0) ? Qh : (sec == 1) ? Kh : Vh;
      *(short4v*)&dst[idx] = o;
    }
  }
}

// ---------------- V transpose: Vh[bh][l][d] -> Vt[bh][d][l] ----------------
__global__ __launch_bounds__(256) void vtrans_kernel(
    const u16* __restrict__ Vh, u16* __restrict__ Vt) {
  __shared__ u16 T[64][72];
  int bh = blockIdx.y;
  int l0 = blockIdx.x * 64;
  int t = threadIdx.x;
  const u16* src = Vh + (size_t)bh * LL * DD;
  {
    int l = t >> 2, dq = (t & 3) * 16;
    short8 v0 = *(const short8*)(src + (size_t)(l0 + l) * DD + dq);
    short8 v1 = *(const short8*)(src + (size_t)(l0 + l) * DD + dq + 8);
    #pragma unroll
    for (int j = 0; j < 8; ++j) T[dq + j][l] = (u16)v0[j];
    #pragma unroll
    for (int j = 0; j < 8; ++j) T[dq + 8 + j][l] = (u16)v1[j];
  }
  __syncthreads();
  {
    int d = t >> 2, lq = (t & 3) * 16;
    u16* dst = Vt + (size_t)bh * DD * LL + (size_t)d * LL + l0 + lq;
    *(short8*)dst = *(const short8*)&T[d][lq];
    *(short8*)(dst + 8) = *(const short8*)&T[d][lq + 8];
  }
}

// ---------------- flash attention (transposed-softmax, 4 blocks/CU) ----------------
__global__ __launch_bounds__(256, 4) void attn_kernel(
    const u16* __restrict__ Qh, const u16* __restrict__ Kh,
    const u16* __restrict__ Vt, u16* __restrict__ Oh) {
  __shared__ __align__(16) u16 Kl[2][64 * 64];
  __shared__ __align__(16) u16 Vl[2][64 * 64];
  __shared__ __align__(16) unsigned int Pp[4][512];   // per-wave 2KB

  const int tid = threadIdx.x;
  const int lane = tid & 63, wave = tid >> 6;
  const int lr = lane & 15, lg = lane >> 4;
  const int sw = (lr & 7) * 2;
  int n = blockIdx.x;
  int kk = n >> 3;
  const int bh = (n & 7) * 16 + (kk >> 3);
  const int q0 = (kk & 7) * 128;

  const u16* Qb = Qh + (size_t)bh * LL * DD;
  const u16* Kb = Kh + (size_t)bh * LL * DD;
  const u16* Vb = Vt + (size_t)bh * DD * LL;

  short8 aq[2][2];
  #pragma unroll
  for (int m = 0; m < 2; ++m)
    #pragma unroll
    for (int s = 0; s < 2; ++s)
      aq[m][s] = *(const short8*)(Qb + (size_t)(q0 + wave * 32 + m * 16 + lr) * DD + s * 32 + lg * 8);

  f32x4 z4 = {0.f, 0.f, 0.f, 0.f};
  f32x4 oaccT[2][4];
  #pragma unroll
  for (int m = 0; m < 2; ++m)
    #pragma unroll
    for (int db = 0; db < 4; ++db) oaccT[m][db] = z4;
  float mrow[2] = {-3e38f, -3e38f}, lsum[2] = {0.f, 0.f};

  auto stage = [&](int buf, int kt) {
    int kk0 = kt * 64;
    #pragma unroll
    for (int i = 0; i < 2; ++i) {
      int c = i * 256 + wave * 64 + lane;
      int row = c >> 3, koct = c & 7;
      int ks = koct ^ (row & 7);
      gload_lds16(Kb + (size_t)(kk0 + row) * DD + ks * 8,
                  (char*)&Kl[buf][0] + (size_t)(i * 4 + wave) * 1024);
      gload_lds16(Vb + (size_t)row * LL + kk0 + ks * 8,
                  (char*)&Vl[buf][0] + (size_t)(i * 4 + wave) * 1024);
    }
  };

  stage(0, 0);
  int cur = 0;
  for (int kt = 0; kt < 16; ++kt) {
    if (kt + 1 < 16) {
      stage(cur ^ 1, kt + 1);
      asm volatile("s_waitcnt vmcnt(4)" ::: "memory");
    } else {
      asm volatile("s_waitcnt vmcnt(0)" ::: "memory");
    }
    __builtin_amdgcn_s_barrier();
    __builtin_amdgcn_sched_barrier(0);

    // ---- S^T = K @ Q^T ----
    f32x4 ps[2][4];
    #pragma unroll
    for (int m = 0; m < 2; ++m)
      #pragma unroll
      for (int kb = 0; kb < 4; ++kb) ps[m][kb] = z4;
    __builtin_amdgcn_s_setprio(1);
    #pragma unroll
    for (int s = 0; s < 2; ++s) {
      #pragma unroll
      for (int kb = 0; kb < 4; ++kb) {
        int key = kb * 16 + lr;
        int dct = s * 4 + lg;
        short8 ka = *(const short8*)((const char*)&Kl[cur][0] + (size_t)key * 128 + ((dct ^ (key & 7)) << 4));
        ps[0][kb] = __builtin_amdgcn_mfma_f32_16x16x32_bf16(ka, aq[0][s], ps[0][kb], 0, 0, 0);
        ps[1][kb] = __builtin_amdgcn_mfma_f32_16x16x32_bf16(ka, aq[1][s], ps[1][kb], 0, 0, 0);
      }
    }
    __builtin_amdgcn_s_setprio(0);

    // ---- lane-local online softmax with defer-max ----
    #pragma unroll
    for (int m = 0; m < 2; ++m) {
      float a0 = fmaxf(fmaxf(ps[m][0][0], ps[m][0][1]), fmaxf(ps[m][0][2], ps[m][0][3]));
      float a1 = fmaxf(fmaxf(ps[m][1][0], ps[m][1][1]), fmaxf(ps[m][1][2], ps[m][1][3]));
      float a2 = fmaxf(fmaxf(ps[m][2][0], ps[m][2][1]), fmaxf(ps[m][2][2], ps[m][2][3]));
      float a3 = fmaxf(fmaxf(ps[m][3][0], ps[m][3][1]), fmaxf(ps[m][3][2], ps[m][3][3]));
      float pmax = fmaxf(fmaxf(a0, a1), fmaxf(a2, a3));
      pmax = fmaxf(pmax, __shfl_xor(pmax, 16));
      pmax = fmaxf(pmax, __shfl_xor(pmax, 32));
      if (!__all(pmax <= mrow[m] + 8.f)) {
        float mn = fmaxf(mrow[m], pmax);
        float alpha = exp2f(mrow[m] - mn);
        mrow[m] = mn;
        lsum[m] *= alpha;
        #pragma unroll
        for (int db = 0; db < 4; ++db)
          #pragma unroll
          for (int r = 0; r < 4; ++r) oaccT[m][db][r] *= alpha;
      }
      float rs = 0.f;
      #pragma unroll
      for (int kb = 0; kb < 4; ++kb)
        #pragma unroll
        for (int r = 0; r < 4; ++r) {
          float p = exp2f(ps[m][kb][r] - mrow[m]);
          ps[m][kb][r] = p;
          rs += p;
        }
      rs += __shfl_xor(rs, 16);
      rs += __shfl_xor(rs, 32);
      lsum[m] += rs;
    }

    // ---- O^T += V^T @ P, sequential m through shared per-wave P buffer ----
    __builtin_amdgcn_s_setprio(1);
    #pragma unroll
    for (int m = 0; m < 2; ++m) {
      #pragma unroll
      for (int kb = 0; kb < 4; ++kb) {
        unsigned lo, hi;
        asm("v_cvt_pk_bf16_f32 %0, %1, %2" : "=v"(lo) : "v"(ps[m][kb][0]), "v"(ps[m][kb][1]));
        asm("v_cvt_pk_bf16_f32 %0, %1, %2" : "=v"(hi) : "v"(ps[m][kb][2]), "v"(ps[m][kb][3]));
        uint2 w; w.x = lo; w.y = hi;
        *(uint2*)&Pp[wave][lr * 32 + (((kb * 4 + lg) ^ sw) * 2)] = w;
      }
      asm volatile("s_waitcnt lgkmcnt(0)" ::: "memory");
      __builtin_amdgcn_sched_barrier(0);
      #pragma unroll
      for (int s = 0; s < 2; ++s) {
        int val0 = s * 8 + lg * 2;
        uint4 pw = *(const uint4*)&Pp[wave][lr * 32 + ((val0 ^ sw) * 2)];
        short8 ap = __builtin_bit_cast(short8, pw);
        #pragma unroll
        for (int db = 0; db < 4; ++db) {
          int d = db * 16 + lr;
          int kct = s * 4 + lg;
          short8 bv = *(const short8*)((const char*)&Vl[cur][0] + (size_t)d * 128 + ((kct ^ (d & 7)) << 4));
          oaccT[m][db] = __builtin_amdgcn_mfma_f32_16x16x32_bf16(bv, ap, oaccT[m][db], 0, 0, 0);
        }
      }
    }
    __builtin_amdgcn_s_setprio(0);

    __builtin_amdgcn_s_barrier();
    cur ^= 1;
  }

  int b = bh >> 3, h = bh & 7;
  #pragma unroll
  for (int m = 0; m < 2; ++m) {
    float inv = 1.0f / lsum[m];
    int q = q0 + wave * 32 + m * 16 + lr;
    #pragma unroll
    for (int db = 0; db < 4; ++db) {
      int d0 = db * 16 + lg * 4;
      short4v o;
      #pragma unroll
      for (int r = 0; r < 4; ++r) o[r] = f2bf(oaccT[m][db][r] * inv);
      *(short4v*)&Oh[(size_t)(b * LL + q) * CC + h * 64 + d0] = o;
    }
  }
}

// ---------------- output projection + residual ----------------
__global__ __launch_bounds__(256) void out_gemm_kernel(
    const u16* __restrict__ Oh, const u16* __restrict__ Wo_bf,
    const float* __restrict__ bo, const float* __restrict__ query,
    float* __restrict__ out) {
  __shared__ __align__(16) u16 Alds[2 * BM * BK];
  __shared__ __align__(16) u16 Blds[2 * BN * BK];
  int m0 = blockIdx.x * BM, n0 = blockIdx.y * BN;
  f32x4 acc[4][4];
  f32x4 z4 = {0.f, 0.f, 0.f, 0.f};
  #pragma unroll
  for (int m = 0; m < 4; ++m)
    #pragma unroll
    for (int n = 0; n < 4; ++n) acc[m][n] = z4;

  gemm_mainloop<CC>(Oh, Wo_bf, m0, n0, Alds, Blds, acc);

  const int lane = threadIdx.x & 63, wave = threadIdx.x >> 6;
  const int wr = wave >> 1, wc = wave & 1;
  const int lr = lane & 15, lg = lane >> 4;
  #pragma unroll
  for (int m = 0; m < 4; ++m) {
    int rowb = m0 + wr * 64 + m * 16 + lg * 4;
    #pragma unroll
    for (int n = 0; n < 4; ++n) {
      int col = n0 + wc * 64 + n * 16 + lr;
      float bias = bo[col];
      #pragma unroll
      for (int r = 0; r < 4; ++r) {
        int rw = rowb + r;
        size_t idx = (size_t)rw * CC + col;
        out[idx] = acc[m][n][r] + bias + query[idx];
      }
    }
  }
}

// ---------------- launcher ----------------
extern "C" void kernel_launch(void* const* d_in, const int* in_sizes, int n_in,
                              void* d_out, int out_size, void* d_ws, size_t ws_size,
                              hipStream_t stream) {
  (void)in_sizes; (void)n_in; (void)out_size;
  const float* query = (const float*)d_in[0];
  const float* qpos  = (const float*)d_in[1];
  const float* Wqc = (const float*)d_in[2];
  const float* bqc = (const float*)d_in[3];
  const float* Wqp = (const float*)d_in[4];
  const float* bqp = (const float*)d_in[5];
  const float* Wkc = (const float*)d_in[6];
  const float* bkc = (const float*)d_in[7];
  const float* Wkp = (const float*)d_in[8];
  const float* bkp = (const float*)d_in[9];
  const float* Wv  = (const float*)d_in[10];
  const float* bv  = (const float*)d_in[11];
  const float* Wo  = (const float*)d_in[12];
  const float* bo  = (const float*)d_in[13];

  char* ws = (char*)d_ws;
  if (ws_size < WS_END) return;

  u16*   Xcat     = (u16*)(ws + WS_XCAT);
  u16*   Wcat     = (u16*)(ws + WS_WCAT);
  u16*   Wo_bf    = (u16*)(ws + WS_WO);
  float* bias_cat = (float*)(ws + WS_BIAS);
  u16*   Qh       = (u16*)(ws + WS_QH);
  u16*   Kh       = (u16*)(ws + WS_KH);
  u16*   Vh       = (u16*)(ws + WS_VH);
  u16*   Oh       = (u16*)(ws + WS_OH);
  u16*   Vtr      = (u16*)(ws + WS_VT);   // aliases Xcat (dead after proj)
  float* out      = (float*)d_out;

  pack_x_kernel<<<dim3(8192), dim3(256), 0, stream>>>(query, qpos, Xcat);
  pack_w_kernel<<<dim3(896), dim3(256), 0, stream>>>(Wqc, Wqp, Wkc, Wkp, Wv, Wo,
                                                     bqc, bqp, bkc, bkp, bv,
                                                     Wcat, Wo_bf, bias_cat);
  proj_gemm_kernel<<<dim3((MROWS / 256) * (NPROJ / 256)), dim3(512), 0, stream>>>(
      Xcat, Wcat, bias_cat, Qh, Kh, Vh);
  vtrans_kernel<<<dim3(LL / 64, BB * HH), dim3(256), 0, stream>>>(Vh, Vtr);
  attn_kernel<<<dim3(1024), dim3(256), 0, stream>>>(Qh, Kh, Vtr, Oh);
  out_gemm_kernel<<<dim3(MROWS / BM, CC / BN), dim3(256), 0, stream>>>(
      Oh, Wo_bf, bo, query, out);
}